// Round 12
// baseline (424.401 us; speedup 1.0000x reference)
//
#include <hip/hip_runtime.h>
#include <math.h>

// ---------------- problem constants ----------------
#define NHEAD 4
#define LRELU_S 0.2f
constexpr int N_GT = 100000, N_AG = 20000;
constexpr int E_GT = 640000, E_COMM = 320000;
constexpr int OUTD = 5;
constexpr int NBLK_SC = (N_AG + 255) / 256;   // 79 scan blocks per graph

// ---------------- workspace layout (float/u32 units of 4B) ----------------
constexpr long O_CNTP_GT = 0;          // 20000*16 u32 (64B line per counter; dead before fs_gemm)
constexpr long O_CNTP_CM = 320000;     // -> 640000
constexpr long O_FSB1    = 0;          // N_GT*64 bf16 = 3.2M units (after CSR build)
constexpr long O_FSB2    = 3200000;    // N_GT*128 bf16 -> 9.6M
constexpr long O_EL1     = 12800000;   // 100000*4
constexpr long O_EL2     = 13200000;   // 100000*4
constexpr long O_RST1    = 13600000;   // 20000*64  (h_vis1)
constexpr long O_ER1     = 14880000;   // 20000*4
constexpr long O_ER2     = 14960000;   // 20000*4
constexpr long O_RST2    = 17600000;   // 20000*128 (h, persists)
constexpr long O_DINV    = 20160000;   // 20000
constexpr long O_OFFS_GT = 20180000;   // 20001 u32
constexpr long O_SRT_GT  = 20200004;   // 640000 u32
constexpr long O_OFFS_CM = 20840004;   // 20001 u32
constexpr long O_SRT_CM  = 20860008;   // 320000 u32
constexpr long O_PART    = 21180008;   // 2*79 u32 block partials
constexpr long O_V       = 21220008;   // 1024 floats
constexpr long O_WB      = 21300000;   // bf16 weights, 153600 shorts -> 21376800
constexpr long O_RANK_GT = 21500000;   // 640000 u32
constexpr long O_RANK_CM = 22140000;   // 320000 u32 -> 22460000
// phase C aliases (fsb/EL regions dead by then)
constexpr long O_T1 = 7680000;         // 20000*128 fp32
constexpr long O_M  = 10240000;        // 20000*64 bf16
constexpr long O_Y  = 15360000;        // 20000*64 fp32

// bf16 weight sub-offsets (shorts, relative to O_WB)
constexpr long WB_FS  = 0;        // [w1|w2] transposed: 192x32 -> 6144
constexpr long WB_E1  = 6144;     // 128x128 -> 22528
constexpr long WB_E2  = 22528;    // 64x128  -> 30720
constexpr long WB_RZ  = 30720;    // 256x320 (r,z gates, concat K=[ih;hh]) -> 112640
constexpr long WB_GIN = 112640;   // 128x192 (n-gate, ih part) -> 137216
constexpr long WB_GHN = 137216;   // 128x128 (n-gate, hh part) -> 153600

using bf8      = __attribute__((ext_vector_type(8))) short;
using f32x4v   = __attribute__((ext_vector_type(4))) float;
using ushort8v = __attribute__((ext_vector_type(8))) unsigned short;

__device__ __forceinline__ unsigned short f2bf(float x) {
    unsigned u = __float_as_uint(x);
    u += 0x7FFFu + ((u >> 16) & 1u);
    return (unsigned short)(u >> 16);
}
__device__ __forceinline__ float bf2f(unsigned short u) {
    return __uint_as_float(((unsigned)u) << 16);
}

__global__ void fill_u32_k(unsigned* __restrict__ p, unsigned v, int n) {
    int i = blockIdx.x * blockDim.x + threadIdx.x;
    if (i < n) p[i] = v;
}

// ---------------- CSR build: count+rank on LINE-PADDED counters ----------------
__global__ void count_rank_k(const int* __restrict__ gdst, unsigned* __restrict__ gcnt,
                             unsigned* __restrict__ grank,
                             const int* __restrict__ cdst, unsigned* __restrict__ ccnt,
                             unsigned* __restrict__ crank) {
    int i = blockIdx.x * blockDim.x + threadIdx.x;
    if (i < E_GT) {
        grank[i] = atomicAdd(gcnt + (long)gdst[i] * 16, 1u);
    } else if (i < E_GT + E_COMM) {
        int j = i - E_GT;
        crank[j] = atomicAdd(ccnt + (long)cdst[j] * 16, 1u);
    }
}

// ---------------- parallel scan phase 1 ----------------
__global__ __launch_bounds__(256) void bscan_k(const unsigned* __restrict__ cnt_gt,
                                               const unsigned* __restrict__ cnt_cm,
                                               unsigned* __restrict__ offs_gt,
                                               unsigned* __restrict__ offs_cm,
                                               unsigned* __restrict__ partials,
                                               float* __restrict__ dinv) {
    __shared__ unsigned sh[256];
    const int g = (blockIdx.x >= NBLK_SC) ? 1 : 0;
    const int b = blockIdx.x - g * NBLK_SC;
    const int t = threadIdx.x;
    const int i = b * 256 + t;
    const unsigned* cnt = g ? cnt_cm : cnt_gt;
    unsigned c = (i < N_AG) ? cnt[(long)i * 16] : 0u;
    if (g && i < N_AG) dinv[i] = 1.0f / fmaxf((float)c, 1.0f);
    sh[t] = c;
    __syncthreads();
    for (int off = 1; off < 256; off <<= 1) {
        unsigned v = (t >= off) ? sh[t - off] : 0u;
        __syncthreads();
        sh[t] += v;
        __syncthreads();
    }
    unsigned* offs = g ? offs_cm : offs_gt;
    if (i < N_AG) offs[i] = sh[t] - c;
    if (t == 255) partials[blockIdx.x] = sh[255];
}

// ---------------- parallel scan phase 2 ----------------
__global__ __launch_bounds__(256) void padd_k(unsigned* __restrict__ offs_gt,
                                              unsigned* __restrict__ offs_cm,
                                              const unsigned* __restrict__ partials) {
    __shared__ unsigned sh[128];
    const int g = (blockIdx.x >= NBLK_SC) ? 1 : 0;
    const int b = blockIdx.x - g * NBLK_SC;
    const int t = threadIdx.x;
    if (t < 128) sh[t] = (t < (unsigned)b) ? partials[g * NBLK_SC + t] : 0u;
    __syncthreads();
    for (int off = 64; off >= 1; off >>= 1) {
        if (t < (unsigned)off) sh[t] += sh[t + off];
        __syncthreads();
    }
    const unsigned pre = sh[0];
    unsigned* offs = g ? offs_cm : offs_gt;
    const int i = b * 256 + t;
    if (i < N_AG) offs[i] += pre;
    if (blockIdx.x == NBLK_SC - 1 && t == 0) offs_gt[N_AG] = E_GT;
    if (blockIdx.x == 2 * NBLK_SC - 1 && t == 0) offs_cm[N_AG] = E_COMM;
}

// atomic-free placement
__global__ void place2_k(const int* __restrict__ gsrc, const int* __restrict__ gdst,
                         const unsigned* __restrict__ grank, const unsigned* __restrict__ goffs,
                         unsigned* __restrict__ gsort,
                         const int* __restrict__ csrc, const int* __restrict__ cdst,
                         const unsigned* __restrict__ crank, const unsigned* __restrict__ coffs,
                         unsigned* __restrict__ csort) {
    int i = blockIdx.x * blockDim.x + threadIdx.x;
    if (i < E_GT) {
        gsort[goffs[gdst[i]] + grank[i]] = (unsigned)gsrc[i];
    } else if (i < E_GT + E_COMM) {
        int j = i - E_GT;
        csort[coffs[cdst[j]] + crank[j]] = (unsigned)csrc[j];
    }
}

// ---------------- all weight converts+transposes in one kernel ----------------
__global__ void wconv_all_k(const float* __restrict__ w1, const float* __restrict__ w2,
                            const float* __restrict__ e1, const float* __restrict__ e2,
                            const float* __restrict__ gih, const float* __restrict__ ghh,
                            unsigned short* __restrict__ wb) {
    int i = blockIdx.x * blockDim.x + threadIdx.x;
    if (i >= 153600) return;
    float val;
    if (i < 2048)        { long l = i;          long n = l / 32,  k = l % 32;  val = w1[k * 64 + n]; }
    else if (i < 6144)   { long l = i - 2048;   long n = l / 32,  k = l % 32;  val = w2[k * 128 + n]; }
    else if (i < 22528)  { long l = i - 6144;   long n = l / 128, k = l % 128; val = e1[k * 128 + n]; }
    else if (i < 30720)  { long l = i - 22528;  long n = l / 128, k = l % 128; val = e2[k * 64 + n]; }
    else if (i < 112640) { long l = i - 30720;  long n = l / 320, k = l % 320;
                           val = (k < 192) ? gih[k * 384 + n] : ghh[(k - 192) * 384 + n]; }
    else if (i < 137216) { long l = i - 112640; long n = l / 192, k = l % 192; val = gih[k * 384 + 256 + n]; }
    else                 { long l = i - 137216; long n = l / 128, k = l % 128; val = ghh[k * 384 + 256 + n]; }
    wb[i] = f2bf(val);
}

// ---------------- all attention projection vectors ----------------
__global__ void make_v_all_k(const float* __restrict__ w1s, const float* __restrict__ a1l,
                             const float* __restrict__ w1d, const float* __restrict__ a1r,
                             const float* __restrict__ w2s, const float* __restrict__ a2l,
                             const float* __restrict__ w2d, const float* __restrict__ a2r,
                             float* __restrict__ v) {
    int i = blockIdx.x * blockDim.x + threadIdx.x;
    if (i >= 1024) return;
    const float *w, *a; int dh, local;
    if (i < 128)      { w = w1s; a = a1l; dh = 16; local = i; }
    else if (i < 384) { w = w1d; a = a1r; dh = 16; local = i - 128; }
    else if (i < 512) { w = w2s; a = a2l; dh = 32; local = i - 384; }
    else              { w = w2d; a = a2r; dh = 32; local = i - 512; }
    int k = local >> 2, h = local & 3;
    float s = 0.f;
    for (int j = 0; j < dh; ++j) s += w[k * (4 * dh) + h * dh + j] * a[h * dh + j];
    v[i] = s;
}

// ---------------- el1/el2 (feat_gt) + er1 (feat_agent) ----------------
__global__ void rowvec_all_k(const float* __restrict__ fgt, const float* __restrict__ fag,
                             const float* __restrict__ v1, const float* __restrict__ v2,
                             const float* __restrict__ vr1,
                             float* __restrict__ el1, float* __restrict__ el2,
                             float* __restrict__ er1) {
    int i = blockIdx.x * blockDim.x + threadIdx.x;
    if (i < N_GT) {
        float a[8] = {};
        const float* fp = fgt + (long)i * 32;
        for (int k = 0; k < 32; ++k) {
            float x = fp[k];
#pragma unroll
            for (int j = 0; j < 4; ++j) a[j] += x * v1[4 * k + j];
#pragma unroll
            for (int j = 0; j < 4; ++j) a[4 + j] += x * v2[4 * k + j];
        }
        *reinterpret_cast<float4*>(el1 + 4l * i) = {a[0], a[1], a[2], a[3]};
        *reinterpret_cast<float4*>(el2 + 4l * i) = {a[4], a[5], a[6], a[7]};
    } else if (i < N_GT + N_AG) {
        int r = i - N_GT;
        float a0 = 0, a1 = 0, a2 = 0, a3 = 0;
        const float* fp = fag + (long)r * 64;
        for (int k = 0; k < 64; ++k) {
            float x = fp[k];
            a0 += x * vr1[4 * k]; a1 += x * vr1[4 * k + 1];
            a2 += x * vr1[4 * k + 2]; a3 += x * vr1[4 * k + 3];
        }
        *reinterpret_cast<float4*>(er1 + 4l * r) = {a0, a1, a2, a3};
    }
}

// ---------------- bf16 MFMA GEMM (enc layers) ----------------
template <int ACT, int OB>
__global__ __launch_bounds__(256) void mgemm_k(const float* __restrict__ A,
                                               const float* __restrict__ A2, int K1,
                                               const unsigned short* __restrict__ Bt,
                                               const float* __restrict__ bias,
                                               void* __restrict__ Cv,
                                               int M, int N, int K) {
    __shared__ unsigned short As[64][40];
    __shared__ unsigned short Bs[64][40];
    const int tid = threadIdx.x;
    const int lane = tid & 63, wv = tid >> 6;
    const int wm = wv & 1, wn = wv >> 1;
    const int quad = lane >> 4, l16 = lane & 15;
    const int m0 = blockIdx.y * 64, n0 = blockIdx.x * 64;
    const int K2 = K - K1;
    f32x4v acc[2][2] = {};
    const int rA = tid >> 3, cA = (tid & 7) * 4;
    const int rB = tid >> 2, cB = (tid & 3) * 8;

    for (int k0 = 0; k0 < K; k0 += 32) {
#pragma unroll
        for (int half = 0; half < 2; ++half) {
            const int r = rA + half * 32;
            const int row = m0 + r;
            const int kg = k0 + cA;
            float4 v = {0.f, 0.f, 0.f, 0.f};
            if (row < M) {
                v = (kg < K1) ? *reinterpret_cast<const float4*>(A + (long)row * K1 + kg)
                              : *reinterpret_cast<const float4*>(A2 + (long)row * K2 + (kg - K1));
            }
            ushort4 b;
            b.x = f2bf(v.x); b.y = f2bf(v.y); b.z = f2bf(v.z); b.w = f2bf(v.w);
            *reinterpret_cast<ushort4*>(&As[r][cA]) = b;
        }
        *reinterpret_cast<ushort8v*>(&Bs[rB][cB]) =
            *reinterpret_cast<const ushort8v*>(Bt + (long)(n0 + rB) * K + k0 + cB);
        __syncthreads();

        const bf8 a0 = *reinterpret_cast<const bf8*>(&As[wm * 32 + l16][quad * 8]);
        const bf8 a1 = *reinterpret_cast<const bf8*>(&As[wm * 32 + 16 + l16][quad * 8]);
        const bf8 b0 = *reinterpret_cast<const bf8*>(&Bs[wn * 32 + l16][quad * 8]);
        const bf8 b1 = *reinterpret_cast<const bf8*>(&Bs[wn * 32 + 16 + l16][quad * 8]);
        acc[0][0] = __builtin_amdgcn_mfma_f32_16x16x32_bf16(a0, b0, acc[0][0], 0, 0, 0);
        acc[0][1] = __builtin_amdgcn_mfma_f32_16x16x32_bf16(a0, b1, acc[0][1], 0, 0, 0);
        acc[1][0] = __builtin_amdgcn_mfma_f32_16x16x32_bf16(a1, b0, acc[1][0], 0, 0, 0);
        acc[1][1] = __builtin_amdgcn_mfma_f32_16x16x32_bf16(a1, b1, acc[1][1], 0, 0, 0);
        __syncthreads();
    }

#pragma unroll
    for (int mt = 0; mt < 2; ++mt)
#pragma unroll
        for (int nt = 0; nt < 2; ++nt)
#pragma unroll
            for (int r = 0; r < 4; ++r) {
                const int row = m0 + wm * 32 + mt * 16 + quad * 4 + r;
                const int col = n0 + wn * 32 + nt * 16 + l16;
                if (row < M) {
                    float v = acc[mt][nt][r];
                    if (bias) v += bias[col];
                    if (ACT) v = fmaxf(v, 0.f);
                    if (OB) ((unsigned short*)Cv)[(long)row * N + col] = f2bf(v);
                    else    ((float*)Cv)[(long)row * N + col] = v;
                }
            }
}

// ---------------- fused GRU GEMM v3: 8 waves/block, 16 j-cols per wave, B streamed from L2 ----------------
__global__ __launch_bounds__(512) void grugemm_k(
    const float* __restrict__ h, const float* __restrict__ y, const float* __restrict__ zz,
    const unsigned short* __restrict__ wrz, const unsigned short* __restrict__ wgin,
    const unsigned short* __restrict__ wghn,
    const float* __restrict__ b_ih, const float* __restrict__ b_hh,
    float* __restrict__ hout, int M)
{
    __shared__ unsigned short As[32][328];   // [h(0:128)|y(128:192)|zz(192:320)] bf16
    const int tid = threadIdx.x;             // 0..511
    const int lane = tid & 63, w = tid >> 6; // w 0..7
    const int quad = lane >> 4, l16 = lane & 15;
    const int m0 = blockIdx.x * 32;
    // stage A rows (32 x 320 bf16): 2560 ushort4-chunks / 512 threads = 5 iters
#pragma unroll
    for (int it = 0; it < 5; ++it) {
        int idx = tid + it * 512;
        int row = idx / 80, cc = (idx - row * 80) * 4;
        int grow = m0 + row;
        float4 v = {0.f, 0.f, 0.f, 0.f};
        if (grow < M) {
            if (cc < 128)      v = *reinterpret_cast<const float4*>(h + (long)grow * 128 + cc);
            else if (cc < 192) v = *reinterpret_cast<const float4*>(y + (long)grow * 64 + (cc - 128));
            else               v = *reinterpret_cast<const float4*>(zz + (long)grow * 128 + (cc - 192));
        }
        ushort4 b;
        b.x = f2bf(v.x); b.y = f2bf(v.y); b.z = f2bf(v.z); b.w = f2bf(v.w);
        *reinterpret_cast<ushort4*>(&As[row][cc]) = b;
    }
    __syncthreads();

    f32x4v aR[2] = {}, aZ[2] = {}, aI[2] = {}, aH[2] = {};
    const int j0 = w * 16;
    const unsigned short* pR = wrz + (long)(j0 + l16) * 320;
    const unsigned short* pZ = wrz + (long)(128 + j0 + l16) * 320;
#pragma unroll
    for (int k0 = 0; k0 < 320; k0 += 32) {
        const bf8 a0 = *reinterpret_cast<const bf8*>(&As[l16][k0 + quad * 8]);
        const bf8 a1 = *reinterpret_cast<const bf8*>(&As[16 + l16][k0 + quad * 8]);
        const bf8 bR = *reinterpret_cast<const bf8*>(pR + k0 + quad * 8);
        const bf8 bZ = *reinterpret_cast<const bf8*>(pZ + k0 + quad * 8);
        aR[0] = __builtin_amdgcn_mfma_f32_16x16x32_bf16(a0, bR, aR[0], 0, 0, 0);
        aR[1] = __builtin_amdgcn_mfma_f32_16x16x32_bf16(a1, bR, aR[1], 0, 0, 0);
        aZ[0] = __builtin_amdgcn_mfma_f32_16x16x32_bf16(a0, bZ, aZ[0], 0, 0, 0);
        aZ[1] = __builtin_amdgcn_mfma_f32_16x16x32_bf16(a1, bZ, aZ[1], 0, 0, 0);
    }
    const unsigned short* pI = wgin + (long)(j0 + l16) * 192;
#pragma unroll
    for (int k0 = 0; k0 < 192; k0 += 32) {
        const bf8 a0 = *reinterpret_cast<const bf8*>(&As[l16][k0 + quad * 8]);
        const bf8 a1 = *reinterpret_cast<const bf8*>(&As[16 + l16][k0 + quad * 8]);
        const bf8 bI = *reinterpret_cast<const bf8*>(pI + k0 + quad * 8);
        aI[0] = __builtin_amdgcn_mfma_f32_16x16x32_bf16(a0, bI, aI[0], 0, 0, 0);
        aI[1] = __builtin_amdgcn_mfma_f32_16x16x32_bf16(a1, bI, aI[1], 0, 0, 0);
    }
    const unsigned short* pH = wghn + (long)(j0 + l16) * 128;
#pragma unroll
    for (int k0 = 0; k0 < 128; k0 += 32) {
        const bf8 a0 = *reinterpret_cast<const bf8*>(&As[l16][192 + k0 + quad * 8]);
        const bf8 a1 = *reinterpret_cast<const bf8*>(&As[16 + l16][192 + k0 + quad * 8]);
        const bf8 bH = *reinterpret_cast<const bf8*>(pH + k0 + quad * 8);
        aH[0] = __builtin_amdgcn_mfma_f32_16x16x32_bf16(a0, bH, aH[0], 0, 0, 0);
        aH[1] = __builtin_amdgcn_mfma_f32_16x16x32_bf16(a1, bH, aH[1], 0, 0, 0);
    }
    // GRU epilogue: wave covers rows m0..m0+31 (2 m-tiles), cols j0..j0+15
    const int j = j0 + l16;
#pragma unroll
    for (int mt = 0; mt < 2; ++mt)
#pragma unroll
        for (int r = 0; r < 4; ++r) {
            const int row = m0 + mt * 16 + quad * 4 + r;
            if (row >= M) continue;
            const float rr = 1.f / (1.f + __expf(-(aR[mt][r] + b_ih[j] + b_hh[j])));
            const float zg = 1.f / (1.f + __expf(-(aZ[mt][r] + b_ih[128 + j] + b_hh[128 + j])));
            const float nn = tanhf(aI[mt][r] + b_ih[256 + j] + rr * (aH[mt][r] + b_hh[256 + j]));
            const float hp = zz[(long)row * 128 + j];
            hout[(long)row * 128 + j] = (1.f - zg) * nn + zg * hp;
        }
}

// ---------------- fused fs1+fs2 producer ----------------
__global__ __launch_bounds__(256) void fs_gemm_k(const float* __restrict__ A,
                                                 const unsigned short* __restrict__ Btc,
                                                 unsigned short* __restrict__ fsb1,
                                                 unsigned short* __restrict__ fsb2, int M) {
    __shared__ unsigned short As[64][40];
    __shared__ unsigned short Bs[64][40];
    const int tid = threadIdx.x;
    const int lane = tid & 63, wv = tid >> 6;
    const int wm = wv & 1, wn = wv >> 1;
    const int quad = lane >> 4, l16 = lane & 15;
    const int m0 = blockIdx.y * 64, n0 = blockIdx.x * 64;
    f32x4v acc[2][2] = {};
    const int rA = tid >> 3, cA = (tid & 7) * 4;
    const int rB = tid >> 2, cB = (tid & 3) * 8;

#pragma unroll
    for (int half = 0; half < 2; ++half) {
        const int r = rA + half * 32;
        const int row = m0 + r;
        float4 v = {0.f, 0.f, 0.f, 0.f};
        if (row < M) v = *reinterpret_cast<const float4*>(A + (long)row * 32 + cA);
        ushort4 b;
        b.x = f2bf(v.x); b.y = f2bf(v.y); b.z = f2bf(v.z); b.w = f2bf(v.w);
        *reinterpret_cast<ushort4*>(&As[r][cA]) = b;
    }
    *reinterpret_cast<ushort8v*>(&Bs[rB][cB]) =
        *reinterpret_cast<const ushort8v*>(Btc + (long)(n0 + rB) * 32 + cB);
    __syncthreads();

    const bf8 a0 = *reinterpret_cast<const bf8*>(&As[wm * 32 + l16][quad * 8]);
    const bf8 a1 = *reinterpret_cast<const bf8*>(&As[wm * 32 + 16 + l16][quad * 8]);
    const bf8 b0 = *reinterpret_cast<const bf8*>(&Bs[wn * 32 + l16][quad * 8]);
    const bf8 b1 = *reinterpret_cast<const bf8*>(&Bs[wn * 32 + 16 + l16][quad * 8]);
    acc[0][0] = __builtin_amdgcn_mfma_f32_16x16x32_bf16(a0, b0, acc[0][0], 0, 0, 0);
    acc[0][1] = __builtin_amdgcn_mfma_f32_16x16x32_bf16(a0, b1, acc[0][1], 0, 0, 0);
    acc[1][0] = __builtin_amdgcn_mfma_f32_16x16x32_bf16(a1, b0, acc[1][0], 0, 0, 0);
    acc[1][1] = __builtin_amdgcn_mfma_f32_16x16x32_bf16(a1, b1, acc[1][1], 0, 0, 0);

#pragma unroll
    for (int mt = 0; mt < 2; ++mt)
#pragma unroll
        for (int nt = 0; nt < 2; ++nt)
#pragma unroll
            for (int r = 0; r < 4; ++r) {
                const int row = m0 + wm * 32 + mt * 16 + quad * 4 + r;
                const int col = n0 + wn * 32 + nt * 16 + l16;
                if (row < M) {
                    unsigned short v16 = f2bf(acc[mt][nt][r]);
                    if (col < 64) fsb1[(long)row * 64 + col] = v16;
                    else          fsb2[(long)row * 128 + (col - 64)] = v16;
                }
            }
}

// ---------------- fused flash GAT (+ optional er2 epilogue for CPL==1) ----------------
template <int CH, int ER2>
__global__ __launch_bounds__(256) void gat_fused_k(
    const unsigned* __restrict__ offs, const unsigned* __restrict__ ssrc,
    const float* __restrict__ el, const float* __restrict__ er,
    const unsigned short* __restrict__ fsb,
    const float* __restrict__ res0, const float* __restrict__ res1,
    const float* __restrict__ bias, float* __restrict__ out, int n_dst, unsigned nsrc,
    const float* __restrict__ vr2, float* __restrict__ er2)
{
    constexpr int CPL = CH / 64;
    const int wid = threadIdx.x >> 6;
    const int lane = threadIdx.x & 63;
    const int d = blockIdx.x * 4 + wid;
    if (d >= n_dst) return;
    const int h = lane >> 4, ei = lane & 15;
    const float er_h = er[4l * d + h];
    const unsigned beg = offs[d], end = offs[d + 1];
    const int c0 = lane * CPL;
    const unsigned smax = nsrc - 1u;
    float m = -INFINITY, s = 0.f, acc0 = 0.f, acc1 = 0.f;

    for (unsigned base = beg; base < end; base += 16) {
        const unsigned na = min(16u, end - base);
        unsigned sv = ssrc[base + ((unsigned)ei < na ? (unsigned)ei : 0u)];
        sv = min(sv, smax);   // safety clamp
        unsigned fw[16];
#pragma unroll
        for (int j = 0; j < 16; ++j) {
            const unsigned sj = (unsigned)__shfl((int)sv, j);
            if (CPL == 2) fw[j] = *reinterpret_cast<const unsigned*>(fsb + (long)sj * CH + c0);
            else          fw[j] = fsb[(long)sj * CH + c0];
        }
        float xv = -INFINITY;
        if ((unsigned)ei < na) {
            float x = el[4l * sv + h] + er_h;
            xv = (x >= 0.f) ? x : LRELU_S * x;
        }
        float cm = xv;
#pragma unroll
        for (int off = 1; off < 16; off <<= 1) cm = fmaxf(cm, __shfl_xor(cm, off));
        const float mn = fmaxf(m, cm);
        const float corr = __expf(m - mn);
        const float p = __expf(xv - mn);
        float ps = p;
#pragma unroll
        for (int off = 1; off < 16; off <<= 1) ps += __shfl_xor(ps, off);
        s = s * corr + ps;
        acc0 *= corr; acc1 *= corr;
        m = mn;
#pragma unroll
        for (int j = 0; j < 16; ++j) {
            const float pj = __shfl(p, (h << 4) | j);
            if (CPL == 2) {
                acc0 += pj * __uint_as_float((fw[j] & 0xFFFFu) << 16);
                acc1 += pj * __uint_as_float((fw[j] >> 16) << 16);
            } else {
                acc0 += pj * bf2f((unsigned short)fw[j]);
            }
        }
    }
    const float inv = (s > 0.f) ? 1.f / s : 0.f;
    if (CPL == 1) {
        const float r = res0[(long)d * 64 + c0];
        const float o = fmaxf(acc0 * inv + r + bias[c0], 0.f);
        out[(long)d * 64 + c0] = o;
        if (ER2) {
            float e[4];
#pragma unroll
            for (int hh = 0; hh < 4; ++hh)
                e[hh] = o * vr2[c0 * 4 + hh] + r * vr2[(64 + c0) * 4 + hh];
#pragma unroll
            for (int off = 1; off < 64; off <<= 1) {
#pragma unroll
                for (int hh = 0; hh < 4; ++hh) e[hh] += __shfl_xor(e[hh], off);
            }
            if (lane == 0)
                *reinterpret_cast<float4*>(er2 + 4l * d) = {e[0], e[1], e[2], e[3]};
        }
    } else {
        float2 r = (c0 < 64) ? *reinterpret_cast<const float2*>(res0 + (long)d * 64 + c0)
                             : *reinterpret_cast<const float2*>(res1 + (long)d * 64 + (c0 - 64));
        float2 o;
        o.x = fmaxf(acc0 * inv + r.x + bias[c0], 0.f);
        o.y = fmaxf(acc1 * inv + r.y + bias[c0 + 1], 0.f);
        *reinterpret_cast<float2*>(out + (long)d * 128 + c0) = o;
    }
}

// ---------------- comm mailbox mean ----------------
__global__ __launch_bounds__(256) void comm_gather_k(const unsigned* __restrict__ offs,
                                                     const unsigned* __restrict__ ssrc,
                                                     const unsigned short* __restrict__ mb,
                                                     const float* __restrict__ dinv,
                                                     float* __restrict__ y, int n) {
    const int wid = threadIdx.x >> 6;
    const int lane = threadIdx.x & 63;
    const int d = blockIdx.x * 4 + wid;
    if (d >= n) return;
    const unsigned beg = offs[d], end = offs[d + 1];
    const int ei = lane & 15;
    const unsigned smax = (unsigned)n - 1u;
    float acc = 0.f;
    for (unsigned base = beg; base < end; base += 16) {
        const unsigned na = min(16u, end - base);
        unsigned sv = ssrc[base + ((unsigned)ei < na ? (unsigned)ei : 0u)];
        sv = min(sv, smax);
        unsigned short fw[16];
#pragma unroll
        for (int j = 0; j < 16; ++j) {
            const unsigned sj = (unsigned)__shfl((int)sv, j);
            fw[j] = mb[(long)sj * 64 + lane];
        }
#pragma unroll
        for (int j = 0; j < 16; ++j)
            if ((unsigned)j < na) acc += bf2f(fw[j]);
    }
    y[(long)d * 64 + lane] = acc * dinv[d];
}

// ---------------- output: h@out_w+out_b followed by copy of h ----------------
__global__ void outcopy_k(const float* __restrict__ h, const float* __restrict__ w,
                          const float* __restrict__ b, float* __restrict__ out) {
    int i = blockIdx.x * blockDim.x + threadIdx.x;
    if (i >= N_AG * 128) return;
    out[(long)N_AG * OUTD + i] = h[i];
    if (i < N_AG) {
        float acc[OUTD];
#pragma unroll
        for (int j = 0; j < OUTD; ++j) acc[j] = b[j];
        for (int k = 0; k < 128; ++k) {
            float v = h[(long)i * 128 + k];
#pragma unroll
            for (int j = 0; j < OUTD; ++j) acc[j] += v * w[k * OUTD + j];
        }
#pragma unroll
        for (int j = 0; j < OUTD; ++j) out[(long)i * OUTD + j] = acc[j];
    }
}

// ---------------- launcher ----------------
extern "C" void kernel_launch(void* const* d_in, const int* in_sizes, int n_in,
                              void* d_out, int out_size, void* d_ws, size_t ws_size,
                              hipStream_t stream) {
    const float* feat_gt    = (const float*)d_in[0];
    const float* feat_agent = (const float*)d_in[1];
    const float* z_in       = (const float*)d_in[2];
    const int*   gt_src     = (const int*)d_in[3];
    const int*   gt_dst     = (const int*)d_in[4];
    const int*   comm_src   = (const int*)d_in[5];
    const int*   comm_dst   = (const int*)d_in[6];
    const float* w1_src = (const float*)d_in[7];
    const float* w1_dst = (const float*)d_in[8];
    const float* a1_l   = (const float*)d_in[9];
    const float* a1_r   = (const float*)d_in[10];
    const float* b1     = (const float*)d_in[11];
    const float* w2_src = (const float*)d_in[12];
    const float* w2_dst = (const float*)d_in[13];
    const float* a2_l   = (const float*)d_in[14];
    const float* a2_r   = (const float*)d_in[15];
    const float* b2     = (const float*)d_in[16];
    const float* enc_w1 = (const float*)d_in[17];
    const float* enc_b1 = (const float*)d_in[18];
    const float* enc_w2 = (const float*)d_in[19];
    const float* enc_b2 = (const float*)d_in[20];
    const float* gw_ih  = (const float*)d_in[21];
    const float* gw_hh  = (const float*)d_in[22];
    const float* gb_ih  = (const float*)d_in[23];
    const float* gb_hh  = (const float*)d_in[24];
    const float* out_w  = (const float*)d_in[25];
    const float* out_b  = (const float*)d_in[26];

    float* ws = (float*)d_ws;
    unsigned* wsu = (unsigned*)d_ws;
    unsigned short* wb = (unsigned short*)(ws + O_WB);
    float* out = (float*)d_out;

    auto blk = [](long n) { return dim3((unsigned)((n + 255) / 256)); };
    const dim3 T(256);

    // ---------- CSR build ----------
    fill_u32_k<<<blk(640000), T, 0, stream>>>(wsu + O_CNTP_GT, 0u, 640000);
    count_rank_k<<<blk(E_GT + E_COMM), T, 0, stream>>>(gt_dst, wsu + O_CNTP_GT, wsu + O_RANK_GT,
                                                       comm_dst, wsu + O_CNTP_CM, wsu + O_RANK_CM);
    bscan_k<<<2 * NBLK_SC, T, 0, stream>>>(wsu + O_CNTP_GT, wsu + O_CNTP_CM,
                                           wsu + O_OFFS_GT, wsu + O_OFFS_CM,
                                           wsu + O_PART, ws + O_DINV);
    padd_k<<<2 * NBLK_SC, T, 0, stream>>>(wsu + O_OFFS_GT, wsu + O_OFFS_CM, wsu + O_PART);
    place2_k<<<blk(E_GT + E_COMM), T, 0, stream>>>(gt_src, gt_dst, wsu + O_RANK_GT, wsu + O_OFFS_GT, wsu + O_SRT_GT,
                                                   comm_src, comm_dst, wsu + O_RANK_CM, wsu + O_OFFS_CM, wsu + O_SRT_CM);

    // ---------- weights + attention vectors + el/er ----------
    wconv_all_k<<<blk(153600), T, 0, stream>>>(w1_src, w2_src, enc_w1, enc_w2, gw_ih, gw_hh, wb);
    make_v_all_k<<<4, 256, 0, stream>>>(w1_src, a1_l, w1_dst, a1_r, w2_src, a2_l, w2_dst, a2_r, ws + O_V);
    float* VL1 = ws + O_V, *VR1 = ws + O_V + 128, *VL2 = ws + O_V + 384, *VR2 = ws + O_V + 512;
    rowvec_all_k<<<blk(N_GT + N_AG), T, 0, stream>>>(feat_gt, feat_agent, VL1, VL2, VR1,
                                                     ws + O_EL1, ws + O_EL2, ws + O_ER1);

    const int MB_GT = (N_GT + 63) / 64, MB_AG = (N_AG + 63) / 64;
    unsigned short* fsb1 = (unsigned short*)(ws + O_FSB1);
    unsigned short* fsb2 = (unsigned short*)(ws + O_FSB2);

    // ---------- fused fs1+fs2 producer ----------
    fs_gemm_k<<<dim3(3, MB_GT), T, 0, stream>>>(feat_gt, wb + WB_FS, fsb1, fsb2, N_GT);

    // ---------- GAT1 (+er2 epilogue) ----------
    gat_fused_k<64, 1><<<dim3((N_AG + 3) / 4), T, 0, stream>>>(wsu + O_OFFS_GT, wsu + O_SRT_GT,
        ws + O_EL1, ws + O_ER1, fsb1, feat_agent, nullptr, b1, ws + O_RST1, N_AG, N_GT,
        VR2, ws + O_ER2);

    // ---------- GAT2 ----------
    gat_fused_k<128, 0><<<dim3((N_AG + 3) / 4), T, 0, stream>>>(wsu + O_OFFS_GT, wsu + O_SRT_GT,
        ws + O_EL2, ws + O_ER2, fsb2, ws + O_RST1, feat_agent, b2, ws + O_RST2, N_AG, N_GT,
        nullptr, nullptr);

    // ---------- comm steps ----------
    float* h = ws + O_RST2;
    unsigned short* mb = (unsigned short*)(ws + O_M);
    for (int step = 0; step < 2; ++step) {
        const float* zz = (step == 0) ? z_in : h;
        mgemm_k<1, 0><<<dim3(2, MB_AG), T, 0, stream>>>(h, nullptr, 128, wb + WB_E1, enc_b1, ws + O_T1, N_AG, 128, 128);
        mgemm_k<1, 1><<<dim3(1, MB_AG), T, 0, stream>>>(ws + O_T1, nullptr, 128, wb + WB_E2, enc_b2, mb, N_AG, 64, 128);
        comm_gather_k<<<dim3((N_AG + 3) / 4), T, 0, stream>>>(wsu + O_OFFS_CM, wsu + O_SRT_CM,
            mb, ws + O_DINV, ws + O_Y, N_AG);
        grugemm_k<<<dim3((N_AG + 31) / 32), dim3(512), 0, stream>>>(h, ws + O_Y, zz,
            wb + WB_RZ, wb + WB_GIN, wb + WB_GHN, gb_ih, gb_hh, h, N_AG);
    }

    // ---------- outputs ----------
    outcopy_k<<<blk((long)N_AG * 128), T, 0, stream>>>(h, out_w, out_b, out);
}

// Round 13
// 414.240 us; speedup vs baseline: 1.0245x; 1.0245x over previous
//
#include <hip/hip_runtime.h>
#include <math.h>

// ---------------- problem constants ----------------
#define NHEAD 4
#define LRELU_S 0.2f
constexpr int N_GT = 100000, N_AG = 20000;
constexpr int E_GT = 640000, E_COMM = 320000;
constexpr int OUTD = 5;
constexpr int NBLK_SC = (N_AG + 255) / 256;   // 79 scan blocks per graph

// ---------------- workspace layout (float/u32 units of 4B) ----------------
constexpr long O_CNTP_GT = 0;          // 20000*16 u32 (64B line per counter; dead before fs_gemm)
constexpr long O_CNTP_CM = 320000;     // -> 640000
constexpr long O_FSB1    = 0;          // N_GT*64 bf16 = 3.2M units (after CSR build)
constexpr long O_FSB2    = 3200000;    // N_GT*128 bf16 -> 9.6M
constexpr long O_EL1     = 12800000;   // 100000*4
constexpr long O_EL2     = 13200000;   // 100000*4
constexpr long O_RST1    = 13600000;   // 20000*64  (h_vis1)
constexpr long O_ER1     = 14880000;   // 20000*4
constexpr long O_ER2     = 14960000;   // 20000*4
constexpr long O_RST2    = 17600000;   // 20000*128 (h, persists)
constexpr long O_DINV    = 20160000;   // 20000
constexpr long O_OFFS_GT = 20180000;   // 20001 u32
constexpr long O_SRT_GT  = 20200004;   // 640000 u32
constexpr long O_OFFS_CM = 20840004;   // 20001 u32
constexpr long O_SRT_CM  = 20860008;   // 320000 u32
constexpr long O_PART    = 21180008;   // 2*79 u32 block partials
constexpr long O_V       = 21220008;   // 1024 floats
constexpr long O_WB      = 21300000;   // bf16 weights, 153600 shorts -> 21376800
constexpr long O_RANK_GT = 21500000;   // 640000 u32
constexpr long O_RANK_CM = 22140000;   // 320000 u32 -> 22460000
// phase C aliases (fsb/EL regions dead by then)
constexpr long O_T1 = 7680000;         // 20000*128 fp32
constexpr long O_M  = 10240000;        // 20000*64 bf16
constexpr long O_Y  = 15360000;        // 20000*64 fp32

// bf16 weight sub-offsets (shorts, relative to O_WB)
constexpr long WB_FS  = 0;        // [w1|w2] transposed: 192x32 -> 6144
constexpr long WB_E1  = 6144;     // 128x128 -> 22528
constexpr long WB_E2  = 22528;    // 64x128  -> 30720
constexpr long WB_RZ  = 30720;    // 256x320 (r,z gates, concat K=[ih;hh]) -> 112640
constexpr long WB_GIN = 112640;   // 128x192 (n-gate, ih part) -> 137216
constexpr long WB_GHN = 137216;   // 128x128 (n-gate, hh part) -> 153600

using bf8      = __attribute__((ext_vector_type(8))) short;
using f32x4v   = __attribute__((ext_vector_type(4))) float;
using ushort8v = __attribute__((ext_vector_type(8))) unsigned short;

__device__ __forceinline__ unsigned short f2bf(float x) {
    unsigned u = __float_as_uint(x);
    u += 0x7FFFu + ((u >> 16) & 1u);
    return (unsigned short)(u >> 16);
}
__device__ __forceinline__ float bf2f(unsigned short u) {
    return __uint_as_float(((unsigned)u) << 16);
}

__global__ void fill_u32_k(unsigned* __restrict__ p, unsigned v, int n) {
    int i = blockIdx.x * blockDim.x + threadIdx.x;
    if (i < n) p[i] = v;
}

// ---------------- CSR build: count+rank on LINE-PADDED counters ----------------
__global__ void count_rank_k(const int* __restrict__ gdst, unsigned* __restrict__ gcnt,
                             unsigned* __restrict__ grank,
                             const int* __restrict__ cdst, unsigned* __restrict__ ccnt,
                             unsigned* __restrict__ crank) {
    int i = blockIdx.x * blockDim.x + threadIdx.x;
    if (i < E_GT) {
        grank[i] = atomicAdd(gcnt + (long)gdst[i] * 16, 1u);
    } else if (i < E_GT + E_COMM) {
        int j = i - E_GT;
        crank[j] = atomicAdd(ccnt + (long)cdst[j] * 16, 1u);
    }
}

// ---------------- parallel scan phase 1 ----------------
__global__ __launch_bounds__(256) void bscan_k(const unsigned* __restrict__ cnt_gt,
                                               const unsigned* __restrict__ cnt_cm,
                                               unsigned* __restrict__ offs_gt,
                                               unsigned* __restrict__ offs_cm,
                                               unsigned* __restrict__ partials,
                                               float* __restrict__ dinv) {
    __shared__ unsigned sh[256];
    const int g = (blockIdx.x >= NBLK_SC) ? 1 : 0;
    const int b = blockIdx.x - g * NBLK_SC;
    const int t = threadIdx.x;
    const int i = b * 256 + t;
    const unsigned* cnt = g ? cnt_cm : cnt_gt;
    unsigned c = (i < N_AG) ? cnt[(long)i * 16] : 0u;
    if (g && i < N_AG) dinv[i] = 1.0f / fmaxf((float)c, 1.0f);
    sh[t] = c;
    __syncthreads();
    for (int off = 1; off < 256; off <<= 1) {
        unsigned v = (t >= off) ? sh[t - off] : 0u;
        __syncthreads();
        sh[t] += v;
        __syncthreads();
    }
    unsigned* offs = g ? offs_cm : offs_gt;
    if (i < N_AG) offs[i] = sh[t] - c;
    if (t == 255) partials[blockIdx.x] = sh[255];
}

// ---------------- parallel scan phase 2 ----------------
__global__ __launch_bounds__(256) void padd_k(unsigned* __restrict__ offs_gt,
                                              unsigned* __restrict__ offs_cm,
                                              const unsigned* __restrict__ partials) {
    __shared__ unsigned sh[128];
    const int g = (blockIdx.x >= NBLK_SC) ? 1 : 0;
    const int b = blockIdx.x - g * NBLK_SC;
    const int t = threadIdx.x;
    if (t < 128) sh[t] = (t < (unsigned)b) ? partials[g * NBLK_SC + t] : 0u;
    __syncthreads();
    for (int off = 64; off >= 1; off >>= 1) {
        if (t < (unsigned)off) sh[t] += sh[t + off];
        __syncthreads();
    }
    const unsigned pre = sh[0];
    unsigned* offs = g ? offs_cm : offs_gt;
    const int i = b * 256 + t;
    if (i < N_AG) offs[i] += pre;
    if (blockIdx.x == NBLK_SC - 1 && t == 0) offs_gt[N_AG] = E_GT;
    if (blockIdx.x == 2 * NBLK_SC - 1 && t == 0) offs_cm[N_AG] = E_COMM;
}

// atomic-free placement
__global__ void place2_k(const int* __restrict__ gsrc, const int* __restrict__ gdst,
                         const unsigned* __restrict__ grank, const unsigned* __restrict__ goffs,
                         unsigned* __restrict__ gsort,
                         const int* __restrict__ csrc, const int* __restrict__ cdst,
                         const unsigned* __restrict__ crank, const unsigned* __restrict__ coffs,
                         unsigned* __restrict__ csort) {
    int i = blockIdx.x * blockDim.x + threadIdx.x;
    if (i < E_GT) {
        gsort[goffs[gdst[i]] + grank[i]] = (unsigned)gsrc[i];
    } else if (i < E_GT + E_COMM) {
        int j = i - E_GT;
        csort[coffs[cdst[j]] + crank[j]] = (unsigned)csrc[j];
    }
}

// ---------------- all weight converts+transposes in one kernel ----------------
__global__ void wconv_all_k(const float* __restrict__ w1, const float* __restrict__ w2,
                            const float* __restrict__ e1, const float* __restrict__ e2,
                            const float* __restrict__ gih, const float* __restrict__ ghh,
                            unsigned short* __restrict__ wb) {
    int i = blockIdx.x * blockDim.x + threadIdx.x;
    if (i >= 153600) return;
    float val;
    if (i < 2048)        { long l = i;          long n = l / 32,  k = l % 32;  val = w1[k * 64 + n]; }
    else if (i < 6144)   { long l = i - 2048;   long n = l / 32,  k = l % 32;  val = w2[k * 128 + n]; }
    else if (i < 22528)  { long l = i - 6144;   long n = l / 128, k = l % 128; val = e1[k * 128 + n]; }
    else if (i < 30720)  { long l = i - 22528;  long n = l / 128, k = l % 128; val = e2[k * 64 + n]; }
    else if (i < 112640) { long l = i - 30720;  long n = l / 320, k = l % 320;
                           val = (k < 192) ? gih[k * 384 + n] : ghh[(k - 192) * 384 + n]; }
    else if (i < 137216) { long l = i - 112640; long n = l / 192, k = l % 192; val = gih[k * 384 + 256 + n]; }
    else                 { long l = i - 137216; long n = l / 128, k = l % 128; val = ghh[k * 384 + 256 + n]; }
    wb[i] = f2bf(val);
}

// ---------------- all attention projection vectors ----------------
__global__ void make_v_all_k(const float* __restrict__ w1s, const float* __restrict__ a1l,
                             const float* __restrict__ w1d, const float* __restrict__ a1r,
                             const float* __restrict__ w2s, const float* __restrict__ a2l,
                             const float* __restrict__ w2d, const float* __restrict__ a2r,
                             float* __restrict__ v) {
    int i = blockIdx.x * blockDim.x + threadIdx.x;
    if (i >= 1024) return;
    const float *w, *a; int dh, local;
    if (i < 128)      { w = w1s; a = a1l; dh = 16; local = i; }
    else if (i < 384) { w = w1d; a = a1r; dh = 16; local = i - 128; }
    else if (i < 512) { w = w2s; a = a2l; dh = 32; local = i - 384; }
    else              { w = w2d; a = a2r; dh = 32; local = i - 512; }
    int k = local >> 2, h = local & 3;
    float s = 0.f;
    for (int j = 0; j < dh; ++j) s += w[k * (4 * dh) + h * dh + j] * a[h * dh + j];
    v[i] = s;
}

// ---------------- el1/el2 (feat_gt) + er1 (feat_agent) ----------------
__global__ void rowvec_all_k(const float* __restrict__ fgt, const float* __restrict__ fag,
                             const float* __restrict__ v1, const float* __restrict__ v2,
                             const float* __restrict__ vr1,
                             float* __restrict__ el1, float* __restrict__ el2,
                             float* __restrict__ er1) {
    int i = blockIdx.x * blockDim.x + threadIdx.x;
    if (i < N_GT) {
        float a[8] = {};
        const float* fp = fgt + (long)i * 32;
        for (int k = 0; k < 32; ++k) {
            float x = fp[k];
#pragma unroll
            for (int j = 0; j < 4; ++j) a[j] += x * v1[4 * k + j];
#pragma unroll
            for (int j = 0; j < 4; ++j) a[4 + j] += x * v2[4 * k + j];
        }
        *reinterpret_cast<float4*>(el1 + 4l * i) = {a[0], a[1], a[2], a[3]};
        *reinterpret_cast<float4*>(el2 + 4l * i) = {a[4], a[5], a[6], a[7]};
    } else if (i < N_GT + N_AG) {
        int r = i - N_GT;
        float a0 = 0, a1 = 0, a2 = 0, a3 = 0;
        const float* fp = fag + (long)r * 64;
        for (int k = 0; k < 64; ++k) {
            float x = fp[k];
            a0 += x * vr1[4 * k]; a1 += x * vr1[4 * k + 1];
            a2 += x * vr1[4 * k + 2]; a3 += x * vr1[4 * k + 3];
        }
        *reinterpret_cast<float4*>(er1 + 4l * r) = {a0, a1, a2, a3};
    }
}

// ---------------- bf16 MFMA GEMM (enc layers) ----------------
template <int ACT, int OB>
__global__ __launch_bounds__(256) void mgemm_k(const float* __restrict__ A,
                                               const float* __restrict__ A2, int K1,
                                               const unsigned short* __restrict__ Bt,
                                               const float* __restrict__ bias,
                                               void* __restrict__ Cv,
                                               int M, int N, int K) {
    __shared__ unsigned short As[64][40];
    __shared__ unsigned short Bs[64][40];
    const int tid = threadIdx.x;
    const int lane = tid & 63, wv = tid >> 6;
    const int wm = wv & 1, wn = wv >> 1;
    const int quad = lane >> 4, l16 = lane & 15;
    const int m0 = blockIdx.y * 64, n0 = blockIdx.x * 64;
    const int K2 = K - K1;
    f32x4v acc[2][2] = {};
    const int rA = tid >> 3, cA = (tid & 7) * 4;
    const int rB = tid >> 2, cB = (tid & 3) * 8;

    for (int k0 = 0; k0 < K; k0 += 32) {
#pragma unroll
        for (int half = 0; half < 2; ++half) {
            const int r = rA + half * 32;
            const int row = m0 + r;
            const int kg = k0 + cA;
            float4 v = {0.f, 0.f, 0.f, 0.f};
            if (row < M) {
                v = (kg < K1) ? *reinterpret_cast<const float4*>(A + (long)row * K1 + kg)
                              : *reinterpret_cast<const float4*>(A2 + (long)row * K2 + (kg - K1));
            }
            ushort4 b;
            b.x = f2bf(v.x); b.y = f2bf(v.y); b.z = f2bf(v.z); b.w = f2bf(v.w);
            *reinterpret_cast<ushort4*>(&As[r][cA]) = b;
        }
        *reinterpret_cast<ushort8v*>(&Bs[rB][cB]) =
            *reinterpret_cast<const ushort8v*>(Bt + (long)(n0 + rB) * K + k0 + cB);
        __syncthreads();

        const bf8 a0 = *reinterpret_cast<const bf8*>(&As[wm * 32 + l16][quad * 8]);
        const bf8 a1 = *reinterpret_cast<const bf8*>(&As[wm * 32 + 16 + l16][quad * 8]);
        const bf8 b0 = *reinterpret_cast<const bf8*>(&Bs[wn * 32 + l16][quad * 8]);
        const bf8 b1 = *reinterpret_cast<const bf8*>(&Bs[wn * 32 + 16 + l16][quad * 8]);
        acc[0][0] = __builtin_amdgcn_mfma_f32_16x16x32_bf16(a0, b0, acc[0][0], 0, 0, 0);
        acc[0][1] = __builtin_amdgcn_mfma_f32_16x16x32_bf16(a0, b1, acc[0][1], 0, 0, 0);
        acc[1][0] = __builtin_amdgcn_mfma_f32_16x16x32_bf16(a1, b0, acc[1][0], 0, 0, 0);
        acc[1][1] = __builtin_amdgcn_mfma_f32_16x16x32_bf16(a1, b1, acc[1][1], 0, 0, 0);
        __syncthreads();
    }

#pragma unroll
    for (int mt = 0; mt < 2; ++mt)
#pragma unroll
        for (int nt = 0; nt < 2; ++nt)
#pragma unroll
            for (int r = 0; r < 4; ++r) {
                const int row = m0 + wm * 32 + mt * 16 + quad * 4 + r;
                const int col = n0 + wn * 32 + nt * 16 + l16;
                if (row < M) {
                    float v = acc[mt][nt][r];
                    if (bias) v += bias[col];
                    if (ACT) v = fmaxf(v, 0.f);
                    if (OB) ((unsigned short*)Cv)[(long)row * N + col] = f2bf(v);
                    else    ((float*)Cv)[(long)row * N + col] = v;
                }
            }
}

// ---------------- fused GRU GEMM v4: batched B prefetch (break the serial load chain) ----------------
__global__ __launch_bounds__(512) void grugemm_k(
    const float* __restrict__ h, const float* __restrict__ y, const float* __restrict__ zz,
    const unsigned short* __restrict__ wrz, const unsigned short* __restrict__ wgin,
    const unsigned short* __restrict__ wghn,
    const float* __restrict__ b_ih, const float* __restrict__ b_hh,
    float* __restrict__ hout, int M)
{
    __shared__ unsigned short As[32][328];   // [h(0:128)|y(128:192)|zz(192:320)] bf16
    const int tid = threadIdx.x;             // 0..511
    const int lane = tid & 63, w = tid >> 6; // w 0..7
    const int quad = lane >> 4, l16 = lane & 15;
    const int m0 = blockIdx.x * 32;
    // stage A rows (32 x 320 bf16)
#pragma unroll
    for (int it = 0; it < 5; ++it) {
        int idx = tid + it * 512;
        int row = idx / 80, cc = (idx - row * 80) * 4;
        int grow = m0 + row;
        float4 v = {0.f, 0.f, 0.f, 0.f};
        if (grow < M) {
            if (cc < 128)      v = *reinterpret_cast<const float4*>(h + (long)grow * 128 + cc);
            else if (cc < 192) v = *reinterpret_cast<const float4*>(y + (long)grow * 64 + (cc - 128));
            else               v = *reinterpret_cast<const float4*>(zz + (long)grow * 128 + (cc - 192));
        }
        ushort4 b;
        b.x = f2bf(v.x); b.y = f2bf(v.y); b.z = f2bf(v.z); b.w = f2bf(v.w);
        *reinterpret_cast<ushort4*>(&As[row][cc]) = b;
    }
    __syncthreads();

    f32x4v aR[2] = {}, aZ[2] = {}, aI[2] = {}, aH[2] = {};
    const int j0 = w * 16;
    const unsigned short* pR = wrz + (long)(j0 + l16) * 320 + quad * 8;
    const unsigned short* pZ = wrz + (long)(128 + j0 + l16) * 320 + quad * 8;
    // ---- RZ (K=320) in two halves; 10 B-fragments batch-prefetched per half ----
#pragma unroll
    for (int half = 0; half < 2; ++half) {
        bf8 bR[5], bZ[5];
#pragma unroll
        for (int i = 0; i < 5; ++i) {
            const int k0 = half * 160 + i * 32;
            bR[i] = *reinterpret_cast<const bf8*>(pR + k0);
            bZ[i] = *reinterpret_cast<const bf8*>(pZ + k0);
        }
#pragma unroll
        for (int i = 0; i < 5; ++i) {
            const int k0 = half * 160 + i * 32;
            const bf8 a0 = *reinterpret_cast<const bf8*>(&As[l16][k0 + quad * 8]);
            const bf8 a1 = *reinterpret_cast<const bf8*>(&As[16 + l16][k0 + quad * 8]);
            aR[0] = __builtin_amdgcn_mfma_f32_16x16x32_bf16(a0, bR[i], aR[0], 0, 0, 0);
            aR[1] = __builtin_amdgcn_mfma_f32_16x16x32_bf16(a1, bR[i], aR[1], 0, 0, 0);
            aZ[0] = __builtin_amdgcn_mfma_f32_16x16x32_bf16(a0, bZ[i], aZ[0], 0, 0, 0);
            aZ[1] = __builtin_amdgcn_mfma_f32_16x16x32_bf16(a1, bZ[i], aZ[1], 0, 0, 0);
        }
    }
    // ---- I (K=192): 6 fragments batched ----
    {
        const unsigned short* pI = wgin + (long)(j0 + l16) * 192 + quad * 8;
        bf8 bI[6];
#pragma unroll
        for (int i = 0; i < 6; ++i) bI[i] = *reinterpret_cast<const bf8*>(pI + i * 32);
#pragma unroll
        for (int i = 0; i < 6; ++i) {
            const int k0 = i * 32;
            const bf8 a0 = *reinterpret_cast<const bf8*>(&As[l16][k0 + quad * 8]);
            const bf8 a1 = *reinterpret_cast<const bf8*>(&As[16 + l16][k0 + quad * 8]);
            aI[0] = __builtin_amdgcn_mfma_f32_16x16x32_bf16(a0, bI[i], aI[0], 0, 0, 0);
            aI[1] = __builtin_amdgcn_mfma_f32_16x16x32_bf16(a1, bI[i], aI[1], 0, 0, 0);
        }
    }
    // ---- H (K=128): 4 fragments batched ----
    {
        const unsigned short* pH = wghn + (long)(j0 + l16) * 128 + quad * 8;
        bf8 bH[4];
#pragma unroll
        for (int i = 0; i < 4; ++i) bH[i] = *reinterpret_cast<const bf8*>(pH + i * 32);
#pragma unroll
        for (int i = 0; i < 4; ++i) {
            const int k0 = 192 + i * 32;
            const bf8 a0 = *reinterpret_cast<const bf8*>(&As[l16][k0 + quad * 8]);
            const bf8 a1 = *reinterpret_cast<const bf8*>(&As[16 + l16][k0 + quad * 8]);
            aH[0] = __builtin_amdgcn_mfma_f32_16x16x32_bf16(a0, bH[i], aH[0], 0, 0, 0);
            aH[1] = __builtin_amdgcn_mfma_f32_16x16x32_bf16(a1, bH[i], aH[1], 0, 0, 0);
        }
    }
    // GRU epilogue: wave covers rows m0..m0+31 (2 m-tiles), cols j0..j0+15
    const int j = j0 + l16;
#pragma unroll
    for (int mt = 0; mt < 2; ++mt)
#pragma unroll
        for (int r = 0; r < 4; ++r) {
            const int row = m0 + mt * 16 + quad * 4 + r;
            if (row >= M) continue;
            const float rr = 1.f / (1.f + __expf(-(aR[mt][r] + b_ih[j] + b_hh[j])));
            const float zg = 1.f / (1.f + __expf(-(aZ[mt][r] + b_ih[128 + j] + b_hh[128 + j])));
            const float nn = tanhf(aI[mt][r] + b_ih[256 + j] + rr * (aH[mt][r] + b_hh[256 + j]));
            const float hp = zz[(long)row * 128 + j];
            hout[(long)row * 128 + j] = (1.f - zg) * nn + zg * hp;
        }
}

// ---------------- fused fs1+fs2 producer ----------------
__global__ __launch_bounds__(256) void fs_gemm_k(const float* __restrict__ A,
                                                 const unsigned short* __restrict__ Btc,
                                                 unsigned short* __restrict__ fsb1,
                                                 unsigned short* __restrict__ fsb2, int M) {
    __shared__ unsigned short As[64][40];
    __shared__ unsigned short Bs[64][40];
    const int tid = threadIdx.x;
    const int lane = tid & 63, wv = tid >> 6;
    const int wm = wv & 1, wn = wv >> 1;
    const int quad = lane >> 4, l16 = lane & 15;
    const int m0 = blockIdx.y * 64, n0 = blockIdx.x * 64;
    f32x4v acc[2][2] = {};
    const int rA = tid >> 3, cA = (tid & 7) * 4;
    const int rB = tid >> 2, cB = (tid & 3) * 8;

#pragma unroll
    for (int half = 0; half < 2; ++half) {
        const int r = rA + half * 32;
        const int row = m0 + r;
        float4 v = {0.f, 0.f, 0.f, 0.f};
        if (row < M) v = *reinterpret_cast<const float4*>(A + (long)row * 32 + cA);
        ushort4 b;
        b.x = f2bf(v.x); b.y = f2bf(v.y); b.z = f2bf(v.z); b.w = f2bf(v.w);
        *reinterpret_cast<ushort4*>(&As[r][cA]) = b;
    }
    *reinterpret_cast<ushort8v*>(&Bs[rB][cB]) =
        *reinterpret_cast<const ushort8v*>(Btc + (long)(n0 + rB) * 32 + cB);
    __syncthreads();

    const bf8 a0 = *reinterpret_cast<const bf8*>(&As[wm * 32 + l16][quad * 8]);
    const bf8 a1 = *reinterpret_cast<const bf8*>(&As[wm * 32 + 16 + l16][quad * 8]);
    const bf8 b0 = *reinterpret_cast<const bf8*>(&Bs[wn * 32 + l16][quad * 8]);
    const bf8 b1 = *reinterpret_cast<const bf8*>(&Bs[wn * 32 + 16 + l16][quad * 8]);
    acc[0][0] = __builtin_amdgcn_mfma_f32_16x16x32_bf16(a0, b0, acc[0][0], 0, 0, 0);
    acc[0][1] = __builtin_amdgcn_mfma_f32_16x16x32_bf16(a0, b1, acc[0][1], 0, 0, 0);
    acc[1][0] = __builtin_amdgcn_mfma_f32_16x16x32_bf16(a1, b0, acc[1][0], 0, 0, 0);
    acc[1][1] = __builtin_amdgcn_mfma_f32_16x16x32_bf16(a1, b1, acc[1][1], 0, 0, 0);

#pragma unroll
    for (int mt = 0; mt < 2; ++mt)
#pragma unroll
        for (int nt = 0; nt < 2; ++nt)
#pragma unroll
            for (int r = 0; r < 4; ++r) {
                const int row = m0 + wm * 32 + mt * 16 + quad * 4 + r;
                const int col = n0 + wn * 32 + nt * 16 + l16;
                if (row < M) {
                    unsigned short v16 = f2bf(acc[mt][nt][r]);
                    if (col < 64) fsb1[(long)row * 64 + col] = v16;
                    else          fsb2[(long)row * 128 + (col - 64)] = v16;
                }
            }
}

// ---------------- fused flash GAT (+ optional er2 epilogue for CPL==1) ----------------
template <int CH, int ER2>
__global__ __launch_bounds__(256) void gat_fused_k(
    const unsigned* __restrict__ offs, const unsigned* __restrict__ ssrc,
    const float* __restrict__ el, const float* __restrict__ er,
    const unsigned short* __restrict__ fsb,
    const float* __restrict__ res0, const float* __restrict__ res1,
    const float* __restrict__ bias, float* __restrict__ out, int n_dst, unsigned nsrc,
    const float* __restrict__ vr2, float* __restrict__ er2)
{
    constexpr int CPL = CH / 64;
    const int wid = threadIdx.x >> 6;
    const int lane = threadIdx.x & 63;
    const int d = blockIdx.x * 4 + wid;
    if (d >= n_dst) return;
    const int h = lane >> 4, ei = lane & 15;
    const float er_h = er[4l * d + h];
    const unsigned beg = offs[d], end = offs[d + 1];
    const int c0 = lane * CPL;
    const unsigned smax = nsrc - 1u;
    float m = -INFINITY, s = 0.f, acc0 = 0.f, acc1 = 0.f;

    for (unsigned base = beg; base < end; base += 16) {
        const unsigned na = min(16u, end - base);
        unsigned sv = ssrc[base + ((unsigned)ei < na ? (unsigned)ei : 0u)];
        sv = min(sv, smax);   // safety clamp
        unsigned fw[16];
#pragma unroll
        for (int j = 0; j < 16; ++j) {
            const unsigned sj = (unsigned)__shfl((int)sv, j);
            if (CPL == 2) fw[j] = *reinterpret_cast<const unsigned*>(fsb + (long)sj * CH + c0);
            else          fw[j] = fsb[(long)sj * CH + c0];
        }
        float xv = -INFINITY;
        if ((unsigned)ei < na) {
            float x = el[4l * sv + h] + er_h;
            xv = (x >= 0.f) ? x : LRELU_S * x;
        }
        float cm = xv;
#pragma unroll
        for (int off = 1; off < 16; off <<= 1) cm = fmaxf(cm, __shfl_xor(cm, off));
        const float mn = fmaxf(m, cm);
        const float corr = __expf(m - mn);
        const float p = __expf(xv - mn);
        float ps = p;
#pragma unroll
        for (int off = 1; off < 16; off <<= 1) ps += __shfl_xor(ps, off);
        s = s * corr + ps;
        acc0 *= corr; acc1 *= corr;
        m = mn;
#pragma unroll
        for (int j = 0; j < 16; ++j) {
            const float pj = __shfl(p, (h << 4) | j);
            if (CPL == 2) {
                acc0 += pj * __uint_as_float((fw[j] & 0xFFFFu) << 16);
                acc1 += pj * __uint_as_float((fw[j] >> 16) << 16);
            } else {
                acc0 += pj * bf2f((unsigned short)fw[j]);
            }
        }
    }
    const float inv = (s > 0.f) ? 1.f / s : 0.f;
    if (CPL == 1) {
        const float r = res0[(long)d * 64 + c0];
        const float o = fmaxf(acc0 * inv + r + bias[c0], 0.f);
        out[(long)d * 64 + c0] = o;
        if (ER2) {
            float e[4];
#pragma unroll
            for (int hh = 0; hh < 4; ++hh)
                e[hh] = o * vr2[c0 * 4 + hh] + r * vr2[(64 + c0) * 4 + hh];
#pragma unroll
            for (int off = 1; off < 64; off <<= 1) {
#pragma unroll
                for (int hh = 0; hh < 4; ++hh) e[hh] += __shfl_xor(e[hh], off);
            }
            if (lane == 0)
                *reinterpret_cast<float4*>(er2 + 4l * d) = {e[0], e[1], e[2], e[3]};
        }
    } else {
        float2 r = (c0 < 64) ? *reinterpret_cast<const float2*>(res0 + (long)d * 64 + c0)
                             : *reinterpret_cast<const float2*>(res1 + (long)d * 64 + (c0 - 64));
        float2 o;
        o.x = fmaxf(acc0 * inv + r.x + bias[c0], 0.f);
        o.y = fmaxf(acc1 * inv + r.y + bias[c0 + 1], 0.f);
        *reinterpret_cast<float2*>(out + (long)d * 128 + c0) = o;
    }
}

// ---------------- comm mailbox mean ----------------
__global__ __launch_bounds__(256) void comm_gather_k(const unsigned* __restrict__ offs,
                                                     const unsigned* __restrict__ ssrc,
                                                     const unsigned short* __restrict__ mb,
                                                     const float* __restrict__ dinv,
                                                     float* __restrict__ y, int n) {
    const int wid = threadIdx.x >> 6;
    const int lane = threadIdx.x & 63;
    const int d = blockIdx.x * 4 + wid;
    if (d >= n) return;
    const unsigned beg = offs[d], end = offs[d + 1];
    const int ei = lane & 15;
    const unsigned smax = (unsigned)n - 1u;
    float acc = 0.f;
    for (unsigned base = beg; base < end; base += 16) {
        const unsigned na = min(16u, end - base);
        unsigned sv = ssrc[base + ((unsigned)ei < na ? (unsigned)ei : 0u)];
        sv = min(sv, smax);
        unsigned short fw[16];
#pragma unroll
        for (int j = 0; j < 16; ++j) {
            const unsigned sj = (unsigned)__shfl((int)sv, j);
            fw[j] = mb[(long)sj * 64 + lane];
        }
#pragma unroll
        for (int j = 0; j < 16; ++j)
            if ((unsigned)j < na) acc += bf2f(fw[j]);
    }
    y[(long)d * 64 + lane] = acc * dinv[d];
}

// ---------------- output: h@out_w+out_b followed by copy of h ----------------
__global__ void outcopy_k(const float* __restrict__ h, const float* __restrict__ w,
                          const float* __restrict__ b, float* __restrict__ out) {
    int i = blockIdx.x * blockDim.x + threadIdx.x;
    if (i >= N_AG * 128) return;
    out[(long)N_AG * OUTD + i] = h[i];
    if (i < N_AG) {
        float acc[OUTD];
#pragma unroll
        for (int j = 0; j < OUTD; ++j) acc[j] = b[j];
        for (int k = 0; k < 128; ++k) {
            float v = h[(long)i * 128 + k];
#pragma unroll
            for (int j = 0; j < OUTD; ++j) acc[j] += v * w[k * OUTD + j];
        }
#pragma unroll
        for (int j = 0; j < OUTD; ++j) out[(long)i * OUTD + j] = acc[j];
    }
}

// ---------------- launcher ----------------
extern "C" void kernel_launch(void* const* d_in, const int* in_sizes, int n_in,
                              void* d_out, int out_size, void* d_ws, size_t ws_size,
                              hipStream_t stream) {
    const float* feat_gt    = (const float*)d_in[0];
    const float* feat_agent = (const float*)d_in[1];
    const float* z_in       = (const float*)d_in[2];
    const int*   gt_src     = (const int*)d_in[3];
    const int*   gt_dst     = (const int*)d_in[4];
    const int*   comm_src   = (const int*)d_in[5];
    const int*   comm_dst   = (const int*)d_in[6];
    const float* w1_src = (const float*)d_in[7];
    const float* w1_dst = (const float*)d_in[8];
    const float* a1_l   = (const float*)d_in[9];
    const float* a1_r   = (const float*)d_in[10];
    const float* b1     = (const float*)d_in[11];
    const float* w2_src = (const float*)d_in[12];
    const float* w2_dst = (const float*)d_in[13];
    const float* a2_l   = (const float*)d_in[14];
    const float* a2_r   = (const float*)d_in[15];
    const float* b2     = (const float*)d_in[16];
    const float* enc_w1 = (const float*)d_in[17];
    const float* enc_b1 = (const float*)d_in[18];
    const float* enc_w2 = (const float*)d_in[19];
    const float* enc_b2 = (const float*)d_in[20];
    const float* gw_ih  = (const float*)d_in[21];
    const float* gw_hh  = (const float*)d_in[22];
    const float* gb_ih  = (const float*)d_in[23];
    const float* gb_hh  = (const float*)d_in[24];
    const float* out_w  = (const float*)d_in[25];
    const float* out_b  = (const float*)d_in[26];

    float* ws = (float*)d_ws;
    unsigned* wsu = (unsigned*)d_ws;
    unsigned short* wb = (unsigned short*)(ws + O_WB);
    float* out = (float*)d_out;

    auto blk = [](long n) { return dim3((unsigned)((n + 255) / 256)); };
    const dim3 T(256);

    // ---------- CSR build ----------
    fill_u32_k<<<blk(640000), T, 0, stream>>>(wsu + O_CNTP_GT, 0u, 640000);
    count_rank_k<<<blk(E_GT + E_COMM), T, 0, stream>>>(gt_dst, wsu + O_CNTP_GT, wsu + O_RANK_GT,
                                                       comm_dst, wsu + O_CNTP_CM, wsu + O_RANK_CM);
    bscan_k<<<2 * NBLK_SC, T, 0, stream>>>(wsu + O_CNTP_GT, wsu + O_CNTP_CM,
                                           wsu + O_OFFS_GT, wsu + O_OFFS_CM,
                                           wsu + O_PART, ws + O_DINV);
    padd_k<<<2 * NBLK_SC, T, 0, stream>>>(wsu + O_OFFS_GT, wsu + O_OFFS_CM, wsu + O_PART);
    place2_k<<<blk(E_GT + E_COMM), T, 0, stream>>>(gt_src, gt_dst, wsu + O_RANK_GT, wsu + O_OFFS_GT, wsu + O_SRT_GT,
                                                   comm_src, comm_dst, wsu + O_RANK_CM, wsu + O_OFFS_CM, wsu + O_SRT_CM);

    // ---------- weights + attention vectors + el/er ----------
    wconv_all_k<<<blk(153600), T, 0, stream>>>(w1_src, w2_src, enc_w1, enc_w2, gw_ih, gw_hh, wb);
    make_v_all_k<<<4, 256, 0, stream>>>(w1_src, a1_l, w1_dst, a1_r, w2_src, a2_l, w2_dst, a2_r, ws + O_V);
    float* VL1 = ws + O_V, *VR1 = ws + O_V + 128, *VL2 = ws + O_V + 384, *VR2 = ws + O_V + 512;
    rowvec_all_k<<<blk(N_GT + N_AG), T, 0, stream>>>(feat_gt, feat_agent, VL1, VL2, VR1,
                                                     ws + O_EL1, ws + O_EL2, ws + O_ER1);

    const int MB_GT = (N_GT + 63) / 64, MB_AG = (N_AG + 63) / 64;
    unsigned short* fsb1 = (unsigned short*)(ws + O_FSB1);
    unsigned short* fsb2 = (unsigned short*)(ws + O_FSB2);

    // ---------- fused fs1+fs2 producer ----------
    fs_gemm_k<<<dim3(3, MB_GT), T, 0, stream>>>(feat_gt, wb + WB_FS, fsb1, fsb2, N_GT);

    // ---------- GAT1 (+er2 epilogue) ----------
    gat_fused_k<64, 1><<<dim3((N_AG + 3) / 4), T, 0, stream>>>(wsu + O_OFFS_GT, wsu + O_SRT_GT,
        ws + O_EL1, ws + O_ER1, fsb1, feat_agent, nullptr, b1, ws + O_RST1, N_AG, N_GT,
        VR2, ws + O_ER2);

    // ---------- GAT2 ----------
    gat_fused_k<128, 0><<<dim3((N_AG + 3) / 4), T, 0, stream>>>(wsu + O_OFFS_GT, wsu + O_SRT_GT,
        ws + O_EL2, ws + O_ER2, fsb2, ws + O_RST1, feat_agent, b2, ws + O_RST2, N_AG, N_GT,
        nullptr, nullptr);

    // ---------- comm steps ----------
    float* h = ws + O_RST2;
    unsigned short* mb = (unsigned short*)(ws + O_M);
    for (int step = 0; step < 2; ++step) {
        const float* zz = (step == 0) ? z_in : h;
        mgemm_k<1, 0><<<dim3(2, MB_AG), T, 0, stream>>>(h, nullptr, 128, wb + WB_E1, enc_b1, ws + O_T1, N_AG, 128, 128);
        mgemm_k<1, 1><<<dim3(1, MB_AG), T, 0, stream>>>(ws + O_T1, nullptr, 128, wb + WB_E2, enc_b2, mb, N_AG, 64, 128);
        comm_gather_k<<<dim3((N_AG + 3) / 4), T, 0, stream>>>(wsu + O_OFFS_CM, wsu + O_SRT_CM,
            mb, ws + O_DINV, ws + O_Y, N_AG);
        grugemm_k<<<dim3((N_AG + 31) / 32), dim3(512), 0, stream>>>(h, ws + O_Y, zz,
            wb + WB_RZ, wb + WB_GIN, wb + WB_GHN, gb_ih, gb_hh, h, N_AG);
    }

    // ---------- outputs ----------
    outcopy_k<<<blk((long)N_AG * 128), T, 0, stream>>>(h, out_w, out_b, out);
}

// Round 14
// 395.292 us; speedup vs baseline: 1.0736x; 1.0479x over previous
//
#include <hip/hip_runtime.h>
#include <math.h>

// ---------------- problem constants ----------------
#define NHEAD 4
#define LRELU_S 0.2f
constexpr int N_GT = 100000, N_AG = 20000;
constexpr int E_GT = 640000, E_COMM = 320000;
constexpr int OUTD = 5;
constexpr int NBLK_SC = (N_AG + 255) / 256;   // 79 scan blocks per graph

// ---------------- workspace layout (float/u32 units of 4B) ----------------
constexpr long O_CNTP_GT = 0;          // 20000*16 u32 (64B line per counter; dead before fs_gemm)
constexpr long O_CNTP_CM = 320000;     // -> 640000
constexpr long O_FSB1    = 0;          // N_GT*64 bf16 = 3.2M units (after CSR build)
constexpr long O_FSB2    = 3200000;    // N_GT*128 bf16 -> 9.6M
constexpr long O_EL1     = 12800000;   // 100000*4
constexpr long O_EL2     = 13200000;   // 100000*4
constexpr long O_RST1    = 13600000;   // 20000*64  (h_vis1)
constexpr long O_ER1     = 14880000;   // 20000*4
constexpr long O_ER2     = 14960000;   // 20000*4
constexpr long O_RST2    = 17600000;   // 20000*128 (h, persists)
constexpr long O_DINV    = 20160000;   // 20000
constexpr long O_OFFS_GT = 20180000;   // 20001 u32
constexpr long O_SRT_GT  = 20200004;   // 640000 u32
constexpr long O_OFFS_CM = 20840004;   // 20001 u32
constexpr long O_SRT_CM  = 20860008;   // 320000 u32
constexpr long O_PART    = 21180008;   // 2*79 u32 block partials
constexpr long O_V       = 21220008;   // 1024 floats
constexpr long O_WB      = 21300000;   // bf16 weights, 153600 shorts -> 21376800
constexpr long O_RANK_GT = 21500000;   // 640000 u32
constexpr long O_RANK_CM = 22140000;   // 320000 u32 -> 22460000
// phase C aliases (fsb/EL regions dead by then)
constexpr long O_M  = 10240000;        // 20000*64 bf16
constexpr long O_Y  = 15360000;        // 20000*64 fp32

// bf16 weight sub-offsets (shorts, relative to O_WB)
constexpr long WB_FS  = 0;        // [w1|w2] transposed: 192x32 -> 6144
constexpr long WB_E1  = 6144;     // 128x128 -> 22528
constexpr long WB_E2  = 22528;    // 64x128  -> 30720
constexpr long WB_RZ  = 30720;    // 256x320 (r,z gates, concat K=[ih;hh]) -> 112640
constexpr long WB_GIN = 112640;   // 128x192 (n-gate, ih part) -> 137216
constexpr long WB_GHN = 137216;   // 128x128 (n-gate, hh part) -> 153600

using bf8      = __attribute__((ext_vector_type(8))) short;
using f32x4v   = __attribute__((ext_vector_type(4))) float;
using ushort8v = __attribute__((ext_vector_type(8))) unsigned short;

__device__ __forceinline__ unsigned short f2bf(float x) {
    unsigned u = __float_as_uint(x);
    u += 0x7FFFu + ((u >> 16) & 1u);
    return (unsigned short)(u >> 16);
}
__device__ __forceinline__ float bf2f(unsigned short u) {
    return __uint_as_float(((unsigned)u) << 16);
}

__global__ void fill_u32_k(unsigned* __restrict__ p, unsigned v, int n) {
    int i = blockIdx.x * blockDim.x + threadIdx.x;
    if (i < n) p[i] = v;
}

// ---------------- CSR build: count+rank on LINE-PADDED counters ----------------
__global__ void count_rank_k(const int* __restrict__ gdst, unsigned* __restrict__ gcnt,
                             unsigned* __restrict__ grank,
                             const int* __restrict__ cdst, unsigned* __restrict__ ccnt,
                             unsigned* __restrict__ crank) {
    int i = blockIdx.x * blockDim.x + threadIdx.x;
    if (i < E_GT) {
        grank[i] = atomicAdd(gcnt + (long)gdst[i] * 16, 1u);
    } else if (i < E_GT + E_COMM) {
        int j = i - E_GT;
        crank[j] = atomicAdd(ccnt + (long)cdst[j] * 16, 1u);
    }
}

// ---------------- parallel scan phase 1 ----------------
__global__ __launch_bounds__(256) void bscan_k(const unsigned* __restrict__ cnt_gt,
                                               const unsigned* __restrict__ cnt_cm,
                                               unsigned* __restrict__ offs_gt,
                                               unsigned* __restrict__ offs_cm,
                                               unsigned* __restrict__ partials,
                                               float* __restrict__ dinv) {
    __shared__ unsigned sh[256];
    const int g = (blockIdx.x >= NBLK_SC) ? 1 : 0;
    const int b = blockIdx.x - g * NBLK_SC;
    const int t = threadIdx.x;
    const int i = b * 256 + t;
    const unsigned* cnt = g ? cnt_cm : cnt_gt;
    unsigned c = (i < N_AG) ? cnt[(long)i * 16] : 0u;
    if (g && i < N_AG) dinv[i] = 1.0f / fmaxf((float)c, 1.0f);
    sh[t] = c;
    __syncthreads();
    for (int off = 1; off < 256; off <<= 1) {
        unsigned v = (t >= off) ? sh[t - off] : 0u;
        __syncthreads();
        sh[t] += v;
        __syncthreads();
    }
    unsigned* offs = g ? offs_cm : offs_gt;
    if (i < N_AG) offs[i] = sh[t] - c;
    if (t == 255) partials[blockIdx.x] = sh[255];
}

// ---------------- parallel scan phase 2 ----------------
__global__ __launch_bounds__(256) void padd_k(unsigned* __restrict__ offs_gt,
                                              unsigned* __restrict__ offs_cm,
                                              const unsigned* __restrict__ partials) {
    __shared__ unsigned sh[128];
    const int g = (blockIdx.x >= NBLK_SC) ? 1 : 0;
    const int b = blockIdx.x - g * NBLK_SC;
    const int t = threadIdx.x;
    if (t < 128) sh[t] = (t < (unsigned)b) ? partials[g * NBLK_SC + t] : 0u;
    __syncthreads();
    for (int off = 64; off >= 1; off >>= 1) {
        if (t < (unsigned)off) sh[t] += sh[t + off];
        __syncthreads();
    }
    const unsigned pre = sh[0];
    unsigned* offs = g ? offs_cm : offs_gt;
    const int i = b * 256 + t;
    if (i < N_AG) offs[i] += pre;
    if (blockIdx.x == NBLK_SC - 1 && t == 0) offs_gt[N_AG] = E_GT;
    if (blockIdx.x == 2 * NBLK_SC - 1 && t == 0) offs_cm[N_AG] = E_COMM;
}

// atomic-free placement
__global__ void place2_k(const int* __restrict__ gsrc, const int* __restrict__ gdst,
                         const unsigned* __restrict__ grank, const unsigned* __restrict__ goffs,
                         unsigned* __restrict__ gsort,
                         const int* __restrict__ csrc, const int* __restrict__ cdst,
                         const unsigned* __restrict__ crank, const unsigned* __restrict__ coffs,
                         unsigned* __restrict__ csort) {
    int i = blockIdx.x * blockDim.x + threadIdx.x;
    if (i < E_GT) {
        gsort[goffs[gdst[i]] + grank[i]] = (unsigned)gsrc[i];
    } else if (i < E_GT + E_COMM) {
        int j = i - E_GT;
        csort[coffs[cdst[j]] + crank[j]] = (unsigned)csrc[j];
    }
}

// ---------------- all weight converts+transposes in one kernel ----------------
__global__ void wconv_all_k(const float* __restrict__ w1, const float* __restrict__ w2,
                            const float* __restrict__ e1, const float* __restrict__ e2,
                            const float* __restrict__ gih, const float* __restrict__ ghh,
                            unsigned short* __restrict__ wb) {
    int i = blockIdx.x * blockDim.x + threadIdx.x;
    if (i >= 153600) return;
    float val;
    if (i < 2048)        { long l = i;          long n = l / 32,  k = l % 32;  val = w1[k * 64 + n]; }
    else if (i < 6144)   { long l = i - 2048;   long n = l / 32,  k = l % 32;  val = w2[k * 128 + n]; }
    else if (i < 22528)  { long l = i - 6144;   long n = l / 128, k = l % 128; val = e1[k * 128 + n]; }
    else if (i < 30720)  { long l = i - 22528;  long n = l / 128, k = l % 128; val = e2[k * 64 + n]; }
    else if (i < 112640) { long l = i - 30720;  long n = l / 320, k = l % 320;
                           val = (k < 192) ? gih[k * 384 + n] : ghh[(k - 192) * 384 + n]; }
    else if (i < 137216) { long l = i - 112640; long n = l / 192, k = l % 192; val = gih[k * 384 + 256 + n]; }
    else                 { long l = i - 137216; long n = l / 128, k = l % 128; val = ghh[k * 384 + 256 + n]; }
    wb[i] = f2bf(val);
}

// ---------------- all attention projection vectors ----------------
__global__ void make_v_all_k(const float* __restrict__ w1s, const float* __restrict__ a1l,
                             const float* __restrict__ w1d, const float* __restrict__ a1r,
                             const float* __restrict__ w2s, const float* __restrict__ a2l,
                             const float* __restrict__ w2d, const float* __restrict__ a2r,
                             float* __restrict__ v) {
    int i = blockIdx.x * blockDim.x + threadIdx.x;
    if (i >= 1024) return;
    const float *w, *a; int dh, local;
    if (i < 128)      { w = w1s; a = a1l; dh = 16; local = i; }
    else if (i < 384) { w = w1d; a = a1r; dh = 16; local = i - 128; }
    else if (i < 512) { w = w2s; a = a2l; dh = 32; local = i - 384; }
    else              { w = w2d; a = a2r; dh = 32; local = i - 512; }
    int k = local >> 2, h = local & 3;
    float s = 0.f;
    for (int j = 0; j < dh; ++j) s += w[k * (4 * dh) + h * dh + j] * a[h * dh + j];
    v[i] = s;
}

// ---------------- el1/el2 (feat_gt) + er1 (feat_agent) ----------------
__global__ void rowvec_all_k(const float* __restrict__ fgt, const float* __restrict__ fag,
                             const float* __restrict__ v1, const float* __restrict__ v2,
                             const float* __restrict__ vr1,
                             float* __restrict__ el1, float* __restrict__ el2,
                             float* __restrict__ er1) {
    int i = blockIdx.x * blockDim.x + threadIdx.x;
    if (i < N_GT) {
        float a[8] = {};
        const float* fp = fgt + (long)i * 32;
        for (int k = 0; k < 32; ++k) {
            float x = fp[k];
#pragma unroll
            for (int j = 0; j < 4; ++j) a[j] += x * v1[4 * k + j];
#pragma unroll
            for (int j = 0; j < 4; ++j) a[4 + j] += x * v2[4 * k + j];
        }
        *reinterpret_cast<float4*>(el1 + 4l * i) = {a[0], a[1], a[2], a[3]};
        *reinterpret_cast<float4*>(el2 + 4l * i) = {a[4], a[5], a[6], a[7]};
    } else if (i < N_GT + N_AG) {
        int r = i - N_GT;
        float a0 = 0, a1 = 0, a2 = 0, a3 = 0;
        const float* fp = fag + (long)r * 64;
        for (int k = 0; k < 64; ++k) {
            float x = fp[k];
            a0 += x * vr1[4 * k]; a1 += x * vr1[4 * k + 1];
            a2 += x * vr1[4 * k + 2]; a3 += x * vr1[4 * k + 3];
        }
        *reinterpret_cast<float4*>(er1 + 4l * r) = {a0, a1, a2, a3};
    }
}

// ---------------- fused enc MLP: mb = relu(relu(h@E1+b1)@E2+b2), t1 kept in LDS ----------------
// Block: 32 rows, 8 waves. Phase1: wave w -> t1 cols [w*16,w*16+16). Phase2: waves 0..3 -> m cols.
// t1 stored bf16 in LDS — bit-identical to the old path (enc2 A-staging did f2bf anyway).
__global__ __launch_bounds__(512) void enc_fused_k(
    const float* __restrict__ h,
    const unsigned short* __restrict__ we1,   // 128x128 (n-major, K=128)
    const unsigned short* __restrict__ we2,   // 64x128
    const float* __restrict__ eb1, const float* __restrict__ eb2,
    unsigned short* __restrict__ mb, int M)
{
    __shared__ unsigned short As[32][136];
    __shared__ unsigned short Ts[32][136];
    const int tid = threadIdx.x;
    const int lane = tid & 63, w = tid >> 6;
    const int quad = lane >> 4, l16 = lane & 15;
    const int m0 = blockIdx.x * 32;
    // stage A: 32x128 fp32 -> bf16 (1024 ushort4 chunks / 512 thr = 2 iters)
#pragma unroll
    for (int it = 0; it < 2; ++it) {
        int idx = tid + it * 512;
        int row = idx >> 5, cc = (idx & 31) * 4;
        int grow = m0 + row;
        float4 v = {0.f, 0.f, 0.f, 0.f};
        if (grow < M) v = *reinterpret_cast<const float4*>(h + (long)grow * 128 + cc);
        ushort4 b;
        b.x = f2bf(v.x); b.y = f2bf(v.y); b.z = f2bf(v.z); b.w = f2bf(v.w);
        *reinterpret_cast<ushort4*>(&As[row][cc]) = b;
    }
    __syncthreads();
    // phase 1: t1 cols j0..j0+15
    {
        const int j0 = w * 16;
        const unsigned short* p = we1 + (long)(j0 + l16) * 128 + quad * 8;
        bf8 bw[4];
#pragma unroll
        for (int i = 0; i < 4; ++i) bw[i] = *reinterpret_cast<const bf8*>(p + i * 32);
        f32x4v acc[2] = {};
#pragma unroll
        for (int i = 0; i < 4; ++i) {
            const int k0 = i * 32;
            const bf8 a0 = *reinterpret_cast<const bf8*>(&As[l16][k0 + quad * 8]);
            const bf8 a1 = *reinterpret_cast<const bf8*>(&As[16 + l16][k0 + quad * 8]);
            acc[0] = __builtin_amdgcn_mfma_f32_16x16x32_bf16(a0, bw[i], acc[0], 0, 0, 0);
            acc[1] = __builtin_amdgcn_mfma_f32_16x16x32_bf16(a1, bw[i], acc[1], 0, 0, 0);
        }
        const int j = j0 + l16;
        const float bj = eb1[j];
#pragma unroll
        for (int mt = 0; mt < 2; ++mt)
#pragma unroll
            for (int r = 0; r < 4; ++r)
                Ts[mt * 16 + quad * 4 + r][j] = f2bf(fmaxf(acc[mt][r] + bj, 0.f));
    }
    __syncthreads();
    // phase 2: m cols (waves 0..3)
    if (w < 4) {
        const int j0 = w * 16;
        const unsigned short* p = we2 + (long)(j0 + l16) * 128 + quad * 8;
        bf8 bw[4];
#pragma unroll
        for (int i = 0; i < 4; ++i) bw[i] = *reinterpret_cast<const bf8*>(p + i * 32);
        f32x4v acc[2] = {};
#pragma unroll
        for (int i = 0; i < 4; ++i) {
            const int k0 = i * 32;
            const bf8 a0 = *reinterpret_cast<const bf8*>(&Ts[l16][k0 + quad * 8]);
            const bf8 a1 = *reinterpret_cast<const bf8*>(&Ts[16 + l16][k0 + quad * 8]);
            acc[0] = __builtin_amdgcn_mfma_f32_16x16x32_bf16(a0, bw[i], acc[0], 0, 0, 0);
            acc[1] = __builtin_amdgcn_mfma_f32_16x16x32_bf16(a1, bw[i], acc[1], 0, 0, 0);
        }
        const int j = j0 + l16;
        const float bj = eb2[j];
#pragma unroll
        for (int mt = 0; mt < 2; ++mt)
#pragma unroll
            for (int r = 0; r < 4; ++r) {
                const int row = m0 + mt * 16 + quad * 4 + r;
                if (row < M)
                    mb[(long)row * 64 + j] = f2bf(fmaxf(acc[mt][r] + bj, 0.f));
            }
    }
}

// ---------------- fused GRU GEMM v4: batched B prefetch ----------------
__global__ __launch_bounds__(512) void grugemm_k(
    const float* __restrict__ h, const float* __restrict__ y, const float* __restrict__ zz,
    const unsigned short* __restrict__ wrz, const unsigned short* __restrict__ wgin,
    const unsigned short* __restrict__ wghn,
    const float* __restrict__ b_ih, const float* __restrict__ b_hh,
    float* __restrict__ hout, int M)
{
    __shared__ unsigned short As[32][328];   // [h(0:128)|y(128:192)|zz(192:320)] bf16
    const int tid = threadIdx.x;             // 0..511
    const int lane = tid & 63, w = tid >> 6; // w 0..7
    const int quad = lane >> 4, l16 = lane & 15;
    const int m0 = blockIdx.x * 32;
#pragma unroll
    for (int it = 0; it < 5; ++it) {
        int idx = tid + it * 512;
        int row = idx / 80, cc = (idx - row * 80) * 4;
        int grow = m0 + row;
        float4 v = {0.f, 0.f, 0.f, 0.f};
        if (grow < M) {
            if (cc < 128)      v = *reinterpret_cast<const float4*>(h + (long)grow * 128 + cc);
            else if (cc < 192) v = *reinterpret_cast<const float4*>(y + (long)grow * 64 + (cc - 128));
            else               v = *reinterpret_cast<const float4*>(zz + (long)grow * 128 + (cc - 192));
        }
        ushort4 b;
        b.x = f2bf(v.x); b.y = f2bf(v.y); b.z = f2bf(v.z); b.w = f2bf(v.w);
        *reinterpret_cast<ushort4*>(&As[row][cc]) = b;
    }
    __syncthreads();

    f32x4v aR[2] = {}, aZ[2] = {}, aI[2] = {}, aH[2] = {};
    const int j0 = w * 16;
    const unsigned short* pR = wrz + (long)(j0 + l16) * 320 + quad * 8;
    const unsigned short* pZ = wrz + (long)(128 + j0 + l16) * 320 + quad * 8;
#pragma unroll
    for (int half = 0; half < 2; ++half) {
        bf8 bR[5], bZ[5];
#pragma unroll
        for (int i = 0; i < 5; ++i) {
            const int k0 = half * 160 + i * 32;
            bR[i] = *reinterpret_cast<const bf8*>(pR + k0);
            bZ[i] = *reinterpret_cast<const bf8*>(pZ + k0);
        }
#pragma unroll
        for (int i = 0; i < 5; ++i) {
            const int k0 = half * 160 + i * 32;
            const bf8 a0 = *reinterpret_cast<const bf8*>(&As[l16][k0 + quad * 8]);
            const bf8 a1 = *reinterpret_cast<const bf8*>(&As[16 + l16][k0 + quad * 8]);
            aR[0] = __builtin_amdgcn_mfma_f32_16x16x32_bf16(a0, bR[i], aR[0], 0, 0, 0);
            aR[1] = __builtin_amdgcn_mfma_f32_16x16x32_bf16(a1, bR[i], aR[1], 0, 0, 0);
            aZ[0] = __builtin_amdgcn_mfma_f32_16x16x32_bf16(a0, bZ[i], aZ[0], 0, 0, 0);
            aZ[1] = __builtin_amdgcn_mfma_f32_16x16x32_bf16(a1, bZ[i], aZ[1], 0, 0, 0);
        }
    }
    {
        const unsigned short* pI = wgin + (long)(j0 + l16) * 192 + quad * 8;
        bf8 bI[6];
#pragma unroll
        for (int i = 0; i < 6; ++i) bI[i] = *reinterpret_cast<const bf8*>(pI + i * 32);
#pragma unroll
        for (int i = 0; i < 6; ++i) {
            const int k0 = i * 32;
            const bf8 a0 = *reinterpret_cast<const bf8*>(&As[l16][k0 + quad * 8]);
            const bf8 a1 = *reinterpret_cast<const bf8*>(&As[16 + l16][k0 + quad * 8]);
            aI[0] = __builtin_amdgcn_mfma_f32_16x16x32_bf16(a0, bI[i], aI[0], 0, 0, 0);
            aI[1] = __builtin_amdgcn_mfma_f32_16x16x32_bf16(a1, bI[i], aI[1], 0, 0, 0);
        }
    }
    {
        const unsigned short* pH = wghn + (long)(j0 + l16) * 128 + quad * 8;
        bf8 bH[4];
#pragma unroll
        for (int i = 0; i < 4; ++i) bH[i] = *reinterpret_cast<const bf8*>(pH + i * 32);
#pragma unroll
        for (int i = 0; i < 4; ++i) {
            const int k0 = 192 + i * 32;
            const bf8 a0 = *reinterpret_cast<const bf8*>(&As[l16][k0 + quad * 8]);
            const bf8 a1 = *reinterpret_cast<const bf8*>(&As[16 + l16][k0 + quad * 8]);
            aH[0] = __builtin_amdgcn_mfma_f32_16x16x32_bf16(a0, bH[i], aH[0], 0, 0, 0);
            aH[1] = __builtin_amdgcn_mfma_f32_16x16x32_bf16(a1, bH[i], aH[1], 0, 0, 0);
        }
    }
    const int j = j0 + l16;
#pragma unroll
    for (int mt = 0; mt < 2; ++mt)
#pragma unroll
        for (int r = 0; r < 4; ++r) {
            const int row = m0 + mt * 16 + quad * 4 + r;
            if (row >= M) continue;
            const float rr = 1.f / (1.f + __expf(-(aR[mt][r] + b_ih[j] + b_hh[j])));
            const float zg = 1.f / (1.f + __expf(-(aZ[mt][r] + b_ih[128 + j] + b_hh[128 + j])));
            const float nn = tanhf(aI[mt][r] + b_ih[256 + j] + rr * (aH[mt][r] + b_hh[256 + j]));
            const float hp = zz[(long)row * 128 + j];
            hout[(long)row * 128 + j] = (1.f - zg) * nn + zg * hp;
        }
}

// ---------------- fused fs1+fs2 producer ----------------
__global__ __launch_bounds__(256) void fs_gemm_k(const float* __restrict__ A,
                                                 const unsigned short* __restrict__ Btc,
                                                 unsigned short* __restrict__ fsb1,
                                                 unsigned short* __restrict__ fsb2, int M) {
    __shared__ unsigned short As[64][40];
    __shared__ unsigned short Bs[64][40];
    const int tid = threadIdx.x;
    const int lane = tid & 63, wv = tid >> 6;
    const int wm = wv & 1, wn = wv >> 1;
    const int quad = lane >> 4, l16 = lane & 15;
    const int m0 = blockIdx.y * 64, n0 = blockIdx.x * 64;
    f32x4v acc[2][2] = {};
    const int rA = tid >> 3, cA = (tid & 7) * 4;
    const int rB = tid >> 2, cB = (tid & 3) * 8;

#pragma unroll
    for (int half = 0; half < 2; ++half) {
        const int r = rA + half * 32;
        const int row = m0 + r;
        float4 v = {0.f, 0.f, 0.f, 0.f};
        if (row < M) v = *reinterpret_cast<const float4*>(A + (long)row * 32 + cA);
        ushort4 b;
        b.x = f2bf(v.x); b.y = f2bf(v.y); b.z = f2bf(v.z); b.w = f2bf(v.w);
        *reinterpret_cast<ushort4*>(&As[r][cA]) = b;
    }
    *reinterpret_cast<ushort8v*>(&Bs[rB][cB]) =
        *reinterpret_cast<const ushort8v*>(Btc + (long)(n0 + rB) * 32 + cB);
    __syncthreads();

    const bf8 a0 = *reinterpret_cast<const bf8*>(&As[wm * 32 + l16][quad * 8]);
    const bf8 a1 = *reinterpret_cast<const bf8*>(&As[wm * 32 + 16 + l16][quad * 8]);
    const bf8 b0 = *reinterpret_cast<const bf8*>(&Bs[wn * 32 + l16][quad * 8]);
    const bf8 b1 = *reinterpret_cast<const bf8*>(&Bs[wn * 32 + 16 + l16][quad * 8]);
    acc[0][0] = __builtin_amdgcn_mfma_f32_16x16x32_bf16(a0, b0, acc[0][0], 0, 0, 0);
    acc[0][1] = __builtin_amdgcn_mfma_f32_16x16x32_bf16(a0, b1, acc[0][1], 0, 0, 0);
    acc[1][0] = __builtin_amdgcn_mfma_f32_16x16x32_bf16(a1, b0, acc[1][0], 0, 0, 0);
    acc[1][1] = __builtin_amdgcn_mfma_f32_16x16x32_bf16(a1, b1, acc[1][1], 0, 0, 0);

#pragma unroll
    for (int mt = 0; mt < 2; ++mt)
#pragma unroll
        for (int nt = 0; nt < 2; ++nt)
#pragma unroll
            for (int r = 0; r < 4; ++r) {
                const int row = m0 + wm * 32 + mt * 16 + quad * 4 + r;
                const int col = n0 + wn * 32 + nt * 16 + l16;
                if (row < M) {
                    unsigned short v16 = f2bf(acc[mt][nt][r]);
                    if (col < 64) fsb1[(long)row * 64 + col] = v16;
                    else          fsb2[(long)row * 128 + (col - 64)] = v16;
                }
            }
}

// ---------------- fused flash GAT (+ optional er2 epilogue for CPL==1) ----------------
template <int CH, int ER2>
__global__ __launch_bounds__(256) void gat_fused_k(
    const unsigned* __restrict__ offs, const unsigned* __restrict__ ssrc,
    const float* __restrict__ el, const float* __restrict__ er,
    const unsigned short* __restrict__ fsb,
    const float* __restrict__ res0, const float* __restrict__ res1,
    const float* __restrict__ bias, float* __restrict__ out, int n_dst, unsigned nsrc,
    const float* __restrict__ vr2, float* __restrict__ er2)
{
    constexpr int CPL = CH / 64;
    const int wid = threadIdx.x >> 6;
    const int lane = threadIdx.x & 63;
    const int d = blockIdx.x * 4 + wid;
    if (d >= n_dst) return;
    const int h = lane >> 4, ei = lane & 15;
    const float er_h = er[4l * d + h];
    const unsigned beg = offs[d], end = offs[d + 1];
    const int c0 = lane * CPL;
    const unsigned smax = nsrc - 1u;
    float m = -INFINITY, s = 0.f, acc0 = 0.f, acc1 = 0.f;

    for (unsigned base = beg; base < end; base += 16) {
        const unsigned na = min(16u, end - base);
        unsigned sv = ssrc[base + ((unsigned)ei < na ? (unsigned)ei : 0u)];
        sv = min(sv, smax);   // safety clamp
        unsigned fw[16];
#pragma unroll
        for (int j = 0; j < 16; ++j) {
            const unsigned sj = (unsigned)__shfl((int)sv, j);
            if (CPL == 2) fw[j] = *reinterpret_cast<const unsigned*>(fsb + (long)sj * CH + c0);
            else          fw[j] = fsb[(long)sj * CH + c0];
        }
        float xv = -INFINITY;
        if ((unsigned)ei < na) {
            float x = el[4l * sv + h] + er_h;
            xv = (x >= 0.f) ? x : LRELU_S * x;
        }
        float cm = xv;
#pragma unroll
        for (int off = 1; off < 16; off <<= 1) cm = fmaxf(cm, __shfl_xor(cm, off));
        const float mn = fmaxf(m, cm);
        const float corr = __expf(m - mn);
        const float p = __expf(xv - mn);
        float ps = p;
#pragma unroll
        for (int off = 1; off < 16; off <<= 1) ps += __shfl_xor(ps, off);
        s = s * corr + ps;
        acc0 *= corr; acc1 *= corr;
        m = mn;
#pragma unroll
        for (int j = 0; j < 16; ++j) {
            const float pj = __shfl(p, (h << 4) | j);
            if (CPL == 2) {
                acc0 += pj * __uint_as_float((fw[j] & 0xFFFFu) << 16);
                acc1 += pj * __uint_as_float((fw[j] >> 16) << 16);
            } else {
                acc0 += pj * bf2f((unsigned short)fw[j]);
            }
        }
    }
    const float inv = (s > 0.f) ? 1.f / s : 0.f;
    if (CPL == 1) {
        const float r = res0[(long)d * 64 + c0];
        const float o = fmaxf(acc0 * inv + r + bias[c0], 0.f);
        out[(long)d * 64 + c0] = o;
        if (ER2) {
            float e[4];
#pragma unroll
            for (int hh = 0; hh < 4; ++hh)
                e[hh] = o * vr2[c0 * 4 + hh] + r * vr2[(64 + c0) * 4 + hh];
#pragma unroll
            for (int off = 1; off < 64; off <<= 1) {
#pragma unroll
                for (int hh = 0; hh < 4; ++hh) e[hh] += __shfl_xor(e[hh], off);
            }
            if (lane == 0)
                *reinterpret_cast<float4*>(er2 + 4l * d) = {e[0], e[1], e[2], e[3]};
        }
    } else {
        float2 r = (c0 < 64) ? *reinterpret_cast<const float2*>(res0 + (long)d * 64 + c0)
                             : *reinterpret_cast<const float2*>(res1 + (long)d * 64 + (c0 - 64));
        float2 o;
        o.x = fmaxf(acc0 * inv + r.x + bias[c0], 0.f);
        o.y = fmaxf(acc1 * inv + r.y + bias[c0 + 1], 0.f);
        *reinterpret_cast<float2*>(out + (long)d * 128 + c0) = o;
    }
}

// ---------------- comm mailbox mean ----------------
__global__ __launch_bounds__(256) void comm_gather_k(const unsigned* __restrict__ offs,
                                                     const unsigned* __restrict__ ssrc,
                                                     const unsigned short* __restrict__ mb,
                                                     const float* __restrict__ dinv,
                                                     float* __restrict__ y, int n) {
    const int wid = threadIdx.x >> 6;
    const int lane = threadIdx.x & 63;
    const int d = blockIdx.x * 4 + wid;
    if (d >= n) return;
    const unsigned beg = offs[d], end = offs[d + 1];
    const int ei = lane & 15;
    const unsigned smax = (unsigned)n - 1u;
    float acc = 0.f;
    for (unsigned base = beg; base < end; base += 16) {
        const unsigned na = min(16u, end - base);
        unsigned sv = ssrc[base + ((unsigned)ei < na ? (unsigned)ei : 0u)];
        sv = min(sv, smax);
        unsigned short fw[16];
#pragma unroll
        for (int j = 0; j < 16; ++j) {
            const unsigned sj = (unsigned)__shfl((int)sv, j);
            fw[j] = mb[(long)sj * 64 + lane];
        }
#pragma unroll
        for (int j = 0; j < 16; ++j)
            if ((unsigned)j < na) acc += bf2f(fw[j]);
    }
    y[(long)d * 64 + lane] = acc * dinv[d];
}

// ---------------- output: h@out_w+out_b followed by copy of h ----------------
__global__ void outcopy_k(const float* __restrict__ h, const float* __restrict__ w,
                          const float* __restrict__ b, float* __restrict__ out) {
    int i = blockIdx.x * blockDim.x + threadIdx.x;
    if (i >= N_AG * 128) return;
    out[(long)N_AG * OUTD + i] = h[i];
    if (i < N_AG) {
        float acc[OUTD];
#pragma unroll
        for (int j = 0; j < OUTD; ++j) acc[j] = b[j];
        for (int k = 0; k < 128; ++k) {
            float v = h[(long)i * 128 + k];
#pragma unroll
            for (int j = 0; j < OUTD; ++j) acc[j] += v * w[k * OUTD + j];
        }
#pragma unroll
        for (int j = 0; j < OUTD; ++j) out[(long)i * OUTD + j] = acc[j];
    }
}

// ---------------- launcher ----------------
extern "C" void kernel_launch(void* const* d_in, const int* in_sizes, int n_in,
                              void* d_out, int out_size, void* d_ws, size_t ws_size,
                              hipStream_t stream) {
    const float* feat_gt    = (const float*)d_in[0];
    const float* feat_agent = (const float*)d_in[1];
    const float* z_in       = (const float*)d_in[2];
    const int*   gt_src     = (const int*)d_in[3];
    const int*   gt_dst     = (const int*)d_in[4];
    const int*   comm_src   = (const int*)d_in[5];
    const int*   comm_dst   = (const int*)d_in[6];
    const float* w1_src = (const float*)d_in[7];
    const float* w1_dst = (const float*)d_in[8];
    const float* a1_l   = (const float*)d_in[9];
    const float* a1_r   = (const float*)d_in[10];
    const float* b1     = (const float*)d_in[11];
    const float* w2_src = (const float*)d_in[12];
    const float* w2_dst = (const float*)d_in[13];
    const float* a2_l   = (const float*)d_in[14];
    const float* a2_r   = (const float*)d_in[15];
    const float* b2     = (const float*)d_in[16];
    const float* enc_w1 = (const float*)d_in[17];
    const float* enc_b1 = (const float*)d_in[18];
    const float* enc_w2 = (const float*)d_in[19];
    const float* enc_b2 = (const float*)d_in[20];
    const float* gw_ih  = (const float*)d_in[21];
    const float* gw_hh  = (const float*)d_in[22];
    const float* gb_ih  = (const float*)d_in[23];
    const float* gb_hh  = (const float*)d_in[24];
    const float* out_w  = (const float*)d_in[25];
    const float* out_b  = (const float*)d_in[26];

    float* ws = (float*)d_ws;
    unsigned* wsu = (unsigned*)d_ws;
    unsigned short* wb = (unsigned short*)(ws + O_WB);
    float* out = (float*)d_out;

    auto blk = [](long n) { return dim3((unsigned)((n + 255) / 256)); };
    const dim3 T(256);

    // ---------- CSR build ----------
    fill_u32_k<<<blk(640000), T, 0, stream>>>(wsu + O_CNTP_GT, 0u, 640000);
    count_rank_k<<<blk(E_GT + E_COMM), T, 0, stream>>>(gt_dst, wsu + O_CNTP_GT, wsu + O_RANK_GT,
                                                       comm_dst, wsu + O_CNTP_CM, wsu + O_RANK_CM);
    bscan_k<<<2 * NBLK_SC, T, 0, stream>>>(wsu + O_CNTP_GT, wsu + O_CNTP_CM,
                                           wsu + O_OFFS_GT, wsu + O_OFFS_CM,
                                           wsu + O_PART, ws + O_DINV);
    padd_k<<<2 * NBLK_SC, T, 0, stream>>>(wsu + O_OFFS_GT, wsu + O_OFFS_CM, wsu + O_PART);
    place2_k<<<blk(E_GT + E_COMM), T, 0, stream>>>(gt_src, gt_dst, wsu + O_RANK_GT, wsu + O_OFFS_GT, wsu + O_SRT_GT,
                                                   comm_src, comm_dst, wsu + O_RANK_CM, wsu + O_OFFS_CM, wsu + O_SRT_CM);

    // ---------- weights + attention vectors + el/er ----------
    wconv_all_k<<<blk(153600), T, 0, stream>>>(w1_src, w2_src, enc_w1, enc_w2, gw_ih, gw_hh, wb);
    make_v_all_k<<<4, 256, 0, stream>>>(w1_src, a1_l, w1_dst, a1_r, w2_src, a2_l, w2_dst, a2_r, ws + O_V);
    float* VL1 = ws + O_V, *VR1 = ws + O_V + 128, *VL2 = ws + O_V + 384, *VR2 = ws + O_V + 512;
    rowvec_all_k<<<blk(N_GT + N_AG), T, 0, stream>>>(feat_gt, feat_agent, VL1, VL2, VR1,
                                                     ws + O_EL1, ws + O_EL2, ws + O_ER1);

    const int MB_GT = (N_GT + 63) / 64;
    unsigned short* fsb1 = (unsigned short*)(ws + O_FSB1);
    unsigned short* fsb2 = (unsigned short*)(ws + O_FSB2);

    // ---------- fused fs1+fs2 producer ----------
    fs_gemm_k<<<dim3(3, MB_GT), T, 0, stream>>>(feat_gt, wb + WB_FS, fsb1, fsb2, N_GT);

    // ---------- GAT1 (+er2 epilogue) ----------
    gat_fused_k<64, 1><<<dim3((N_AG + 3) / 4), T, 0, stream>>>(wsu + O_OFFS_GT, wsu + O_SRT_GT,
        ws + O_EL1, ws + O_ER1, fsb1, feat_agent, nullptr, b1, ws + O_RST1, N_AG, N_GT,
        VR2, ws + O_ER2);

    // ---------- GAT2 ----------
    gat_fused_k<128, 0><<<dim3((N_AG + 3) / 4), T, 0, stream>>>(wsu + O_OFFS_GT, wsu + O_SRT_GT,
        ws + O_EL2, ws + O_ER2, fsb2, ws + O_RST1, feat_agent, b2, ws + O_RST2, N_AG, N_GT,
        nullptr, nullptr);

    // ---------- comm steps ----------
    float* h = ws + O_RST2;
    unsigned short* mb = (unsigned short*)(ws + O_M);
    for (int step = 0; step < 2; ++step) {
        const float* zz = (step == 0) ? z_in : h;
        enc_fused_k<<<dim3((N_AG + 31) / 32), dim3(512), 0, stream>>>(
            h, wb + WB_E1, wb + WB_E2, enc_b1, enc_b2, mb, N_AG);
        comm_gather_k<<<dim3((N_AG + 3) / 4), T, 0, stream>>>(wsu + O_OFFS_CM, wsu + O_SRT_CM,
            mb, ws + O_DINV, ws + O_Y, N_AG);
        grugemm_k<<<dim3((N_AG + 31) / 32), dim3(512), 0, stream>>>(h, ws + O_Y, zz,
            wb + WB_RZ, wb + WB_GIN, wb + WB_GHN, gb_ih, gb_hh, h, N_AG);
    }

    // ---------- outputs ----------
    outcopy_k<<<blk((long)N_AG * 128), T, 0, stream>>>(h, out_w, out_b, out);
}